// Round 13
// baseline (462.565 us; speedup 1.0000x reference)
//
#include <hip/hip_runtime.h>
#include <hip/hip_bf16.h>

// ---------------------------------------------------------------------------
// ROLAND-style GNN forward. Round 12: B-register-resident streaming GEMM.
// Each wave owns one 16-col tile; its full hi/lo weight fragments live in
// VGPRs for the whole kernel (loaded once). Per 16-row tile only the A-frag
// loads remain, issued as a block and fenced with sched_barrier(0) so the
// compiler cannot serialize them (R10/R11: VGPR=32 proved loads were sunk
// to uses -> 1 in flight -> 890 GB/s wall). No LDS, no syncthreads.
// Bucketed CSR build; bf16 CSR gather with 8-deep ILP.
// ---------------------------------------------------------------------------

typedef unsigned short ushort_t;
typedef __attribute__((ext_vector_type(8))) short s8v;   // 8 bf16 (4 VGPRs)
typedef __attribute__((ext_vector_type(4))) float f4;    // MFMA accumulator

#define BSHIFT 8                       // nodes per bucket = 256 (N<=65536)

__device__ __forceinline__ void bsplit(float v, ushort_t& hi, ushort_t& lo) {
    unsigned u = __float_as_uint(v);
    unsigned rh = u + 0x7FFFu + ((u >> 16) & 1u);
    hi = (ushort_t)(rh >> 16);
    float fh = __uint_as_float((unsigned)hi << 16);
    float d = v - fh;
    unsigned u2 = __float_as_uint(d);
    unsigned rl = u2 + 0x7FFFu + ((u2 >> 16) & 1u);
    lo = (ushort_t)(rl >> 16);
}

__device__ __forceinline__ ushort_t f2bf(float v) {
    unsigned u = __float_as_uint(v);
    return (ushort_t)((u + 0x7FFFu + ((u >> 16) & 1u)) >> 16);
}

__device__ __forceinline__ s8v cvt8(f4 v0, f4 v1) {
    ushort_t hb[8];
    hb[0] = f2bf(v0.x); hb[1] = f2bf(v0.y); hb[2] = f2bf(v0.z); hb[3] = f2bf(v0.w);
    hb[4] = f2bf(v1.x); hb[5] = f2bf(v1.y); hb[6] = f2bf(v1.z); hb[7] = f2bf(v1.w);
    return *(s8v*)hb;
}

// ---------------- B-register-resident streaming MFMA GEMM -------------------
// C[M,Nout] = epilogue( A1[M,KS1*32] (++ A2f[M,KS2*32]) @ W )
// grid = (Nout/64, rowgroups); block = 4 waves; wave owns colTile
// blockIdx.x*4+w (16 cols) with its B frags (hi+lo) in registers.
// Row-tile = 16 rows; TR tiles per block. Wth/Wtl frag-major:
// ((colTile*KS+ks)<<9) + lane*8.  A1BF: A1 is bf16. OUTMODE: 0 fp32,
// 2 bf16, 3 fp32+bf16.
template <int KS1, int KS2, int TR, bool RELU, bool SCALE, bool A1BF, int OUTMODE>
__global__ __launch_bounds__(256, 3) void gemm_breg(
    const float* __restrict__ A1f, const ushort_t* __restrict__ A1h,
    const float* __restrict__ A2f,
    const ushort_t* __restrict__ Wth, const ushort_t* __restrict__ Wtl,
    const float* __restrict__ bias, const float* __restrict__ rowscale,
    float* __restrict__ Cf, ushort_t* __restrict__ Ch,
    int M, int Nout)
{
    constexpr int KS = KS1 + KS2;
    constexpr int K1 = KS1 * 32;
    constexpr int K2 = KS2 * 32;
    constexpr bool DUAL = (KS2 > 0);

    const int lane = threadIdx.x & 63;
    const int w    = threadIdx.x >> 6;
    const int colTile = blockIdx.x * 4 + w;
    const int c16  = lane & 15;
    const int q8   = (lane >> 4) * 8;      // k-offset of this lane's 8 elems
    const int col  = colTile * 16 + c16;

    // ---- B fragments: loaded ONCE, resident in VGPRs ----
    s8v bh[KS], bl[KS];
#pragma unroll
    for (int ks = 0; ks < KS; ++ks) {
        const size_t fo = (((size_t)colTile * KS + ks) << 9) + ((size_t)lane << 3);
        bh[ks] = *(const s8v*)&Wth[fo];
        bl[ks] = *(const s8v*)&Wtl[fo];
    }

    const float frs = 1.f;  // placate unused warnings
    (void)frs;

    for (int t = 0; t < TR; ++t) {
        const int tile  = blockIdx.y * TR + t;
        const int rbase = tile * 16;
        if (rbase >= M) break;
        const int r = min(rbase + c16, M - 1);

        // ---- A-load block: all loads issued together ----
        s8v ab[KS1 > 0 ? KS1 : 1];            // bf16 A frags
        f4  ar[(A1BF ? 1 : KS1 * 2)];         // fp32 raw (non-ABF)
        f4  ar2[DUAL ? KS2 * 2 : 1];          // fp32 raw (dual tail)
#pragma unroll
        for (int ks = 0; ks < KS1; ++ks) {
            const int kb = ks * 32 + q8;
            if constexpr (A1BF) {
                ab[ks] = *(const s8v*)&A1h[(size_t)r * K1 + kb];
            } else {
                ar[2 * ks]     = *(const f4*)&A1f[(size_t)r * K1 + kb];
                ar[2 * ks + 1] = *(const f4*)&A1f[(size_t)r * K1 + kb + 4];
            }
        }
        if constexpr (DUAL) {
#pragma unroll
            for (int ks = 0; ks < KS2; ++ks) {
                const int kb = ks * 32 + q8;
                ar2[2 * ks]     = *(const f4*)&A2f[(size_t)r * K2 + kb];
                ar2[2 * ks + 1] = *(const f4*)&A2f[(size_t)r * K2 + kb + 4];
            }
        }
        __builtin_amdgcn_sched_barrier(0);   // loads stay above, MFMAs below

        // ---- compute ----
        f4 acc = {0.f, 0.f, 0.f, 0.f};
#pragma unroll
        for (int ks = 0; ks < KS1; ++ks) {
            s8v a;
            if constexpr (A1BF) a = ab[ks];
            else                a = cvt8(ar[2 * ks], ar[2 * ks + 1]);
            acc = __builtin_amdgcn_mfma_f32_16x16x32_bf16(a, bh[ks], acc, 0, 0, 0);
            acc = __builtin_amdgcn_mfma_f32_16x16x32_bf16(a, bl[ks], acc, 0, 0, 0);
        }
        if constexpr (DUAL) {
#pragma unroll
            for (int ks = 0; ks < KS2; ++ks) {
                s8v a = cvt8(ar2[2 * ks], ar2[2 * ks + 1]);
                acc = __builtin_amdgcn_mfma_f32_16x16x32_bf16(a, bh[KS1 + ks], acc, 0, 0, 0);
                acc = __builtin_amdgcn_mfma_f32_16x16x32_bf16(a, bl[KS1 + ks], acc, 0, 0, 0);
            }
        }

        // ---- epilogue: C/D layout col=lane&15, row=(lane>>4)*4+reg ----
#pragma unroll
        for (int reg = 0; reg < 4; ++reg) {
            const int row = rbase + (lane >> 4) * 4 + reg;
            if (row >= M) continue;
            float v = acc[reg];
            if (SCALE) v *= rowscale[row];
            if (bias) v += bias[col];
            if (RELU) v = fmaxf(v, 0.f);
            if constexpr (OUTMODE == 2) {
                Ch[(size_t)row * Nout + col] = f2bf(v);
            } else if constexpr (OUTMODE == 3) {
                Cf[(size_t)row * Nout + col] = v;
                Ch[(size_t)row * Nout + col] = f2bf(v);
            } else {
                Cf[(size_t)row * Nout + col] = v;
            }
        }
    }
}

// ---------------- weight transpose + split (fragment-major) -----------------
struct WDesc { const float* W; ushort_t* h; ushort_t* l; int K; int No; };
struct WAll { WDesc d[6]; };

__global__ void wtcvt_kernel(WAll wa) {
    WDesc d = wa.d[blockIdx.y];
    int e = blockIdx.x * blockDim.x + threadIdx.x;
    if (e >= d.K * d.No) return;
    int k = e / d.No, n = e - k * d.No;
    ushort_t h, l;
    bsplit(d.W[e], h, l);
    int colTile = n >> 4, c16 = n & 15;
    int ks = k >> 5, quad = (k >> 3) & 3, j = k & 7;
    int lane = c16 + (quad << 4);
    size_t idx = (((size_t)colTile * (d.K >> 5) + ks) << 9) + ((size_t)lane << 3) + j;
    d.h[idx] = h;
    d.l[idx] = l;
}

// ---------------- bucketed CSR build ----------------------------------------
__global__ __launch_bounds__(256) void bcount_kernel(const int* __restrict__ dst,
                                                     int* __restrict__ bcount, int E, int NB) {
    __shared__ int cnt[256];
    const int t = threadIdx.x;
    if (t < NB) cnt[t] = 0;
    __syncthreads();
    for (int e = blockIdx.x * 256 + t; e < E; e += gridDim.x * 256)
        atomicAdd(&cnt[dst[e] >> BSHIFT], 1);
    __syncthreads();
    if (t < NB && cnt[t]) atomicAdd(&bcount[t], cnt[t]);
}

__global__ __launch_bounds__(256) void bscan_kernel(const int* __restrict__ bcount,
                                                    int* __restrict__ bbase,
                                                    int* __restrict__ bcursor, int NB, int E) {
    __shared__ int s[256];
    const int t = threadIdx.x;
    s[t] = (t < NB) ? bcount[t] : 0;
    __syncthreads();
    for (int off = 1; off < 256; off <<= 1) {
        int v = (t >= off) ? s[t - off] : 0;
        __syncthreads();
        s[t] += v;
        __syncthreads();
    }
    int excl = t ? s[t - 1] : 0;
    if (t < NB) { bbase[t] = excl; bcursor[t] = excl; }
    if (t == 0) bbase[NB] = E;
}

__global__ __launch_bounds__(256) void bpart_kernel(const int* __restrict__ src,
                                                    const int* __restrict__ dst,
                                                    int* __restrict__ bcursor,
                                                    unsigned* __restrict__ packed, int E, int NB) {
    __shared__ int cnt[256];
    __shared__ int cur[256];
    const int t = threadIdx.x;
    const int beg = blockIdx.x * 8192;
    const int end = min(beg + 8192, E);
    if (t < NB) cnt[t] = 0;
    __syncthreads();
    for (int e = beg + t; e < end; e += 256) atomicAdd(&cnt[dst[e] >> BSHIFT], 1);
    __syncthreads();
    if (t < NB && cnt[t]) cur[t] = atomicAdd(&bcursor[t], cnt[t]);
    __syncthreads();
    for (int e = beg + t; e < end; e += 256) {
        int d = dst[e];
        int b = d >> BSHIFT;
        int pos = atomicAdd(&cur[b], 1);
        packed[pos] = (unsigned)src[e] | ((unsigned)(d & ((1 << BSHIFT) - 1)) << 16);
    }
}

__global__ __launch_bounds__(256) void bbuild_kernel(const int* __restrict__ bbase,
                                                     const unsigned* __restrict__ packed,
                                                     int* __restrict__ col,
                                                     int* __restrict__ rowstart,
                                                     float* __restrict__ dinv, int N, int E) {
    __shared__ int ncnt[256];
    __shared__ int s[256];
    __shared__ int ncur[256];
    const int b = blockIdx.x;
    const int t = threadIdx.x;
    const int beg = bbase[b], end = bbase[b + 1];
    const int node0 = b << BSHIFT;
    const int nInB = min(256, N - node0);
    ncnt[t] = 0;
    __syncthreads();
    for (int e = beg + t; e < end; e += 256) atomicAdd(&ncnt[packed[e] >> 16], 1);
    __syncthreads();
    s[t] = ncnt[t];
    __syncthreads();
    for (int off = 1; off < 256; off <<= 1) {
        int v = (t >= off) ? s[t - off] : 0;
        __syncthreads();
        s[t] += v;
        __syncthreads();
    }
    int excl = t ? s[t - 1] : 0;
    if (t < nInB) {
        rowstart[node0 + t] = beg + excl;
        dinv[node0 + t] = rsqrtf((float)ncnt[t] + 1.0f);
    }
    ncur[t] = beg + excl;
    __syncthreads();
    for (int e = beg + t; e < end; e += 256) {
        unsigned p = packed[e];
        int pos = atomicAdd(&ncur[p >> 16], 1);
        col[pos] = (int)(p & 0xFFFFu);
    }
    if (b == 0 && t == 0) rowstart[N] = E;
}

// ---------------- CSR gather (bf16 in, bf16 out, 8-deep ILP) ----------------
template <int F>
__global__ __launch_bounds__(256) void gather_bf_kernel(const int* __restrict__ rowstart,
                                                        const int* __restrict__ col,
                                                        const float* __restrict__ dinv,
                                                        const ushort_t* __restrict__ hws,
                                                        const float* __restrict__ bias,
                                                        ushort_t* __restrict__ aggb, int N) {
    const int wave = threadIdx.x >> 6;
    const int lane = threadIdx.x & 63;
    const int d = blockIdx.x * 4 + wave;
    if (d >= N) return;
    const int beg = rowstart[d], end = rowstart[d + 1];
    const float dd = dinv[d];
    if (F == 128) {
        const unsigned* base = (const unsigned*)hws;   // 2 bf16 per uint
        unsigned sv = base[(size_t)d * 64 + lane];
        float ax = __uint_as_float(sv << 16);
        float ay = __uint_as_float(sv & 0xFFFF0000u);
        for (int e0 = beg; e0 < end; e0 += 64) {
            int nid = (e0 + lane < end) ? col[e0 + lane] : 0;
            int cnt = min(64, end - e0);
            int j = 0;
            for (; j + 8 <= cnt; j += 8) {
                unsigned u[8];
#pragma unroll
                for (int q = 0; q < 8; ++q) {
                    int s = __shfl(nid, j + q);
                    u[q] = base[(size_t)s * 64 + lane];
                }
#pragma unroll
                for (int q = 0; q < 8; ++q) {
                    ax += __uint_as_float(u[q] << 16);
                    ay += __uint_as_float(u[q] & 0xFFFF0000u);
                }
            }
            for (; j < cnt; ++j) {
                int s = __shfl(nid, j);
                unsigned uu = base[(size_t)s * 64 + lane];
                ax += __uint_as_float(uu << 16);
                ay += __uint_as_float(uu & 0xFFFF0000u);
            }
        }
        float2 b = ((const float2*)bias)[lane];
        float rx = fmaxf(ax * dd + b.x, 0.f);
        float ry = fmaxf(ay * dd + b.y, 0.f);
        unsigned pk = ((unsigned)f2bf(ry) << 16) | (unsigned)f2bf(rx);
        ((unsigned*)aggb)[(size_t)d * 64 + lane] = pk;
    } else {  // F == 64
        float acc = __uint_as_float((unsigned)hws[(size_t)d * 64 + lane] << 16);
        for (int e0 = beg; e0 < end; e0 += 64) {
            int nid = (e0 + lane < end) ? col[e0 + lane] : 0;
            int cnt = min(64, end - e0);
            int j = 0;
            for (; j + 8 <= cnt; j += 8) {
                ushort_t u[8];
#pragma unroll
                for (int q = 0; q < 8; ++q) {
                    int s = __shfl(nid, j + q);
                    u[q] = hws[(size_t)s * 64 + lane];
                }
#pragma unroll
                for (int q = 0; q < 8; ++q) acc += __uint_as_float((unsigned)u[q] << 16);
            }
            for (; j < cnt; ++j) {
                int s = __shfl(nid, j);
                acc += __uint_as_float((unsigned)hws[(size_t)s * 64 + lane] << 16);
            }
        }
        acc = fmaxf(acc * dd + bias[lane], 0.f);
        aggb[(size_t)d * 64 + lane] = f2bf(acc);
    }
}

// ---------------- edge decode (bf16 emb1 copy) ------------------------------
__global__ __launch_bounds__(256) void decode_kernel(const ushort_t* __restrict__ emb1b,
                                                     const int* __restrict__ eli,
                                                     const float* __restrict__ Wpost,
                                                     const float* __restrict__ bpost,
                                                     float* __restrict__ pred, int L) {
    const int wave = threadIdx.x >> 6;
    const int lane = threadIdx.x & 63;
    const int l = blockIdx.x * 4 + wave;
    if (l >= L) return;
    int s = eli[l];
    int d = eli[L + l];
    float w = Wpost[lane * 2] + Wpost[lane * 2 + 1];
    float a = __uint_as_float((unsigned)emb1b[(size_t)s * 64 + lane] << 16);
    float b = __uint_as_float((unsigned)emb1b[(size_t)d * 64 + lane] << 16);
    float p = a * b * w;
#pragma unroll
    for (int off = 32; off; off >>= 1) p += __shfl_down(p, off);
    if (lane == 0) pred[l] = p + bpost[0] + bpost[1];
}

// ---------------------------------------------------------------------------
extern "C" void kernel_launch(void* const* d_in, const int* in_sizes, int n_in,
                              void* d_out, int out_size, void* d_ws, size_t ws_size,
                              hipStream_t stream) {
    const float* x     = (const float*)d_in[0];
    const float* prev0 = (const float*)d_in[1];
    const float* prev1 = (const float*)d_in[2];
    const float* Wpre1 = (const float*)d_in[3];
    const float* bpre1 = (const float*)d_in[4];
    const float* Wpre2 = (const float*)d_in[5];
    const float* bpre2 = (const float*)d_in[6];
    const float* Wc1   = (const float*)d_in[7];
    const float* bc1   = (const float*)d_in[8];
    const float* Wc2   = (const float*)d_in[9];
    const float* bc2   = (const float*)d_in[10];
    const float* Wm1   = (const float*)d_in[11];
    const float* bm1   = (const float*)d_in[12];
    const float* Wm2   = (const float*)d_in[13];
    const float* bm2   = (const float*)d_in[14];
    const float* Wpost = (const float*)d_in[15];
    const float* bpost = (const float*)d_in[16];
    const int* edge_index = (const int*)d_in[17];
    const int* eli        = (const int*)d_in[18];

    const int N = in_sizes[0] / 256;   // 50000  (must be <= 65536 for packing)
    const int E = in_sizes[17] / 2;    // 1.6M
    const int L = in_sizes[18] / 2;    // 200K
    const int NB = (N + 255) >> BSHIFT;

    const int* src = edge_index;
    const int* dst = edge_index + E;

    float* out  = (float*)d_out;
    float* pred = out;                        // [L]
    float* emb0 = out + L;                    // [N,128]
    float* emb1 = out + L + (size_t)N * 128;  // [N,64]

    // ---- workspace layout (float slots); all regions disjoint in time ----
    float* ws = (float*)d_ws;
    ushort_t* h1h   = (ushort_t*)ws;                       // [0,128N)
    ushort_t* hws1b = (ushort_t*)ws;                       // [0,64N)
    ushort_t* emb0b = (ushort_t*)ws;                       // [0,64N)
    ushort_t* emb1b = (ushort_t*)ws;                       // [0,32N)
    ushort_t* agg1b = (ushort_t*)(ws + (size_t)64 * N);    // [64N,128N)
    ushort_t* hws2b = (ushort_t*)(ws + (size_t)64 * N);    // [64N,96N)
    ushort_t* agg2b = (ushort_t*)(ws + (size_t)96 * N);    // [96N,128N)
    ushort_t* h2b   = (ushort_t*)(ws + (size_t)128 * N);   // [128N,192N)

    size_t o = (size_t)192 * N;
    unsigned* packed = (unsigned*)(ws + o); o += ((size_t)E + 3) & ~(size_t)3;
    int* col = (int*)(ws + o);              o += ((size_t)E + 3) & ~(size_t)3;
    int* rowstart = (int*)(ws + o);         o += ((size_t)N + 4) & ~(size_t)3;
    float* dinv = ws + o;                   o += ((size_t)N + 3) & ~(size_t)3;
    int* bbase = (int*)(ws + o);            o += 260;
    int* bcursor = (int*)(ws + o);          o += 260;
    int* bcount = (int*)(ws + o);           o += 260;
    ushort_t* wb = (ushort_t*)(ws + o);     // 327680 ushorts (16B-aligned)

    ushort_t* wpre1h = wb + 0;       ushort_t* wpre1l = wb + 65536;
    ushort_t* wpre2h = wb + 131072;  ushort_t* wpre2l = wb + 163840;
    ushort_t* wc1h   = wb + 196608;  ushort_t* wc1l   = wb + 212992;
    ushort_t* wm1h   = wb + 229376;  ushort_t* wm1l   = wb + 262144;
    ushort_t* wc2h   = wb + 294912;  ushort_t* wc2l   = wb + 303104;
    ushort_t* wm2h   = wb + 311296;  ushort_t* wm2l   = wb + 319488;

    // 0) bucketed CSR build + dinv
    hipMemsetAsync(bcount, 0, (size_t)NB * sizeof(int), stream);
    bcount_kernel<<<1024, 256, 0, stream>>>(dst, bcount, E, NB);
    bscan_kernel<<<1, 256, 0, stream>>>(bcount, bbase, bcursor, NB, E);
    bpart_kernel<<<(E + 8191) / 8192, 256, 0, stream>>>(src, dst, bcursor, packed, E, NB);
    bbuild_kernel<<<NB, 256, 0, stream>>>(bbase, packed, col, rowstart, dinv, N, E);

    // 0b) weights: transpose + hi/lo split into fragment-major layout
    WAll wa;
    wa.d[0] = {Wpre1, wpre1h, wpre1l, 256, 256};
    wa.d[1] = {Wpre2, wpre2h, wpre2l, 256, 128};
    wa.d[2] = {Wc1,   wc1h,   wc1l,   128, 128};
    wa.d[3] = {Wm1,   wm1h,   wm1l,   256, 128};
    wa.d[4] = {Wc2,   wc2h,   wc2l,   128, 64};
    wa.d[5] = {Wm2,   wm2h,   wm2l,   128, 64};
    wtcvt_kernel<<<dim3(256, 6), 256, 0, stream>>>(wa);

    const int t16 = (N + 15) / 16;   // 3125 16-row tiles

    // 1) h1 = bf16(relu(x@Wpre1+b))           [N,256]  K=256 fp32 A
    gemm_breg<8, 0, 8, true, false, false, 2><<<dim3(4, (t16 + 7) / 8), 256, 0, stream>>>(
        x, nullptr, nullptr, wpre1h, wpre1l, bpre1, nullptr, nullptr, h1h, N, 256);
    // 2) h2 = bf16(relu(h1@Wpre2+b))          [N,128]  K=256 bf16 A
    gemm_breg<8, 0, 4, true, false, true, 2><<<dim3(2, (t16 + 3) / 4), 256, 0, stream>>>(
        nullptr, h1h, nullptr, wpre2h, wpre2l, bpre2, nullptr, nullptr, h2b, N, 128);
    // 3) hws1 = bf16((h2@Wc1)*dinv[row])      [N,128]  K=128  (h1 dead)
    gemm_breg<4, 0, 4, false, true, true, 2><<<dim3(2, (t16 + 3) / 4), 256, 0, stream>>>(
        nullptr, h2b, nullptr, wc1h, wc1l, nullptr, dinv, nullptr, hws1b, N, 128);
    // 4) agg1 = bf16(relu(dinv*(hws1[d]+sum hws1[s])+bc1))
    gather_bf_kernel<128><<<(N + 3) / 4, 256, 0, stream>>>(rowstart, col, dinv, hws1b, bc1, agg1b, N);
    // 5) emb0 = [agg1,prev0]@Wm1+bm1 (fp32 + bf16 copy)  [N,128]  K=128+128
    gemm_breg<4, 4, 4, false, false, true, 3><<<dim3(2, (t16 + 3) / 4), 256, 0, stream>>>(
        nullptr, agg1b, prev0, wm1h, wm1l, bm1, nullptr, emb0, emb0b, N, 128);
    // 6) hws2 = bf16((emb0@Wc2)*dinv[row])    [N,64]   K=128 bf16 A
    gemm_breg<4, 0, 2, false, true, true, 2><<<dim3(1, (t16 + 1) / 2), 256, 0, stream>>>(
        nullptr, emb0b, nullptr, wc2h, wc2l, nullptr, dinv, nullptr, hws2b, N, 64);
    // 7) agg2 = bf16(relu(dinv*(hws2[d]+sum hws2[s])+bc2))
    gather_bf_kernel<64><<<(N + 3) / 4, 256, 0, stream>>>(rowstart, col, dinv, hws2b, bc2, agg2b, N);
    // 8) emb1 = [agg2,prev1]@Wm2+bm2 (fp32 + bf16 copy)  [N,64]  K=64+64
    gemm_breg<2, 2, 2, false, false, true, 3><<<dim3(1, (t16 + 1) / 2), 256, 0, stream>>>(
        nullptr, agg2b, prev1, wm2h, wm2l, bm2, nullptr, emb1, emb1b, N, 64);
    // 9) decode (bf16 emb1 copy, L2-resident)
    decode_kernel<<<(L + 3) / 4, 256, 0, stream>>>(emb1b, eli, Wpost, bpost, pred, L);
}

// Round 15
// 419.879 us; speedup vs baseline: 1.1017x; 1.1017x over previous
//
#include <hip/hip_runtime.h>
#include <hip/hip_bf16.h>

// ---------------------------------------------------------------------------
// ROLAND-style GNN forward. Round 14: fix round-13's workspace overlaps
// ([N,128]us regions were sized as 32N float-slots instead of 64N -> xbf/h1h
// and h2b/p0b/p1b collided -> NaN). Wide-wave-tile GEMM (128 rows x 32 cols
// per wave) + sched_group_barrier-pinned register double-buffer. G1 consumes
// fp32 x directly (no xbf staging buffer). Frag-major weights.
// Bucketed CSR build; bf16 CSR gather with 8-deep ILP.
// ---------------------------------------------------------------------------

typedef unsigned short ushort_t;
typedef __attribute__((ext_vector_type(8))) short s8v;   // 8 bf16 (4 VGPRs)
typedef __attribute__((ext_vector_type(4))) float f4;    // MFMA accumulator

#define BSHIFT 8                       // nodes per bucket = 256 (N<=65536)

__device__ __forceinline__ void bsplit(float v, ushort_t& hi, ushort_t& lo) {
    unsigned u = __float_as_uint(v);
    unsigned rh = u + 0x7FFFu + ((u >> 16) & 1u);
    hi = (ushort_t)(rh >> 16);
    float fh = __uint_as_float((unsigned)hi << 16);
    float d = v - fh;
    unsigned u2 = __float_as_uint(d);
    unsigned rl = u2 + 0x7FFFu + ((u2 >> 16) & 1u);
    lo = (ushort_t)(rl >> 16);
}

__device__ __forceinline__ ushort_t f2bf(float v) {
    unsigned u = __float_as_uint(v);
    return (ushort_t)((u + 0x7FFFu + ((u >> 16) & 1u)) >> 16);
}

__device__ __forceinline__ s8v cvt8(f4 v0, f4 v1) {
    ushort_t hb[8];
    hb[0] = f2bf(v0.x); hb[1] = f2bf(v0.y); hb[2] = f2bf(v0.z); hb[3] = f2bf(v0.w);
    hb[4] = f2bf(v1.x); hb[5] = f2bf(v1.y); hb[6] = f2bf(v1.z); hb[7] = f2bf(v1.w);
    return *(s8v*)hb;
}

// ---------------- fp32 -> bf16 bulk convert ---------------------------------
__global__ __launch_bounds__(256) void f2b_kernel(const float* __restrict__ in,
                                                  ushort_t* __restrict__ out, size_t n) {
    size_t i = ((size_t)blockIdx.x * 256 + threadIdx.x) * 8;
    if (i + 8 > n) return;
    f4 v0 = *(const f4*)&in[i];
    f4 v1 = *(const f4*)&in[i + 4];
    *(s8v*)&out[i] = cvt8(v0, v1);
}

// ---------------- wide-wave-tile MFMA GEMM (SGB-pinned reg dbuf) ------------
// C[M,Nout] = epilogue( A1[M,KS1*32] (++ A2[M,KS2*32]) @ W )
// grid = (Nout/(64*NT), ceil(M/128)); block = 4 waves; wave w = col panel
// (NT*16 cols) x 128 rows (8 row-frags). A1: bf16 if A1BF else fp32 (cvt in
// reg). A2 (if KS2>0): bf16. Wth/Wtl frag-major:
// ((colTile*KS+ks)<<9) + lane*8. OUTMODE: 0 fp32, 2 bf16, 3 fp32+bf16.
template <int NT, int KS1, int KS2, bool A1BF, bool RELU, bool SCALE, int OUTMODE>
__global__ __launch_bounds__(256, 2) void gemm_wide(
    const float* __restrict__ A1f, const ushort_t* __restrict__ A1h,
    const ushort_t* __restrict__ A2h,
    const ushort_t* __restrict__ Wth, const ushort_t* __restrict__ Wtl,
    const float* __restrict__ bias, const float* __restrict__ rowscale,
    float* __restrict__ Cf, ushort_t* __restrict__ Ch,
    int M, int Nout)
{
    constexpr int KS = KS1 + KS2;
    constexpr int K1 = KS1 * 32;
    constexpr int K2 = KS2 * 32;
    constexpr int NLOAD = (A1BF ? 8 : 16) + 2 * NT;   // VMEM_READ per k-step
    constexpr int NMFMA = 16 * NT;                    // MFMA per k-step

    const int lane = threadIdx.x & 63;
    const int w    = threadIdx.x >> 6;
    const int colTile0 = (blockIdx.x * 4 + w) * NT;
    const int bn   = colTile0 * 16;
    const int rbase = blockIdx.y * 128;
    const int c16  = lane & 15;
    const int q8   = (lane >> 4) * 8;

    int r[8];
#pragma unroll
    for (int mi = 0; mi < 8; ++mi) r[mi] = min(rbase + mi * 16 + c16, M - 1);

    f4 acc[8][NT];
    const f4 zero = {0.f, 0.f, 0.f, 0.f};
#pragma unroll
    for (int mi = 0; mi < 8; ++mi)
#pragma unroll
        for (int ni = 0; ni < NT; ++ni) acc[mi][ni] = zero;

    s8v aA[8], bhA[NT], blA[NT];
    s8v aB[8], bhB[NT], blB[NT];

    auto LOAD = [&](int ks, s8v* a, s8v* bh, s8v* bl) {
#pragma unroll
        for (int mi = 0; mi < 8; ++mi) {
            if (KS2 == 0 || ks < KS1) {
                if constexpr (A1BF) {
                    a[mi] = *(const s8v*)&A1h[(size_t)r[mi] * K1 + ks * 32 + q8];
                } else {
                    const float* p = &A1f[(size_t)r[mi] * K1 + ks * 32 + q8];
                    a[mi] = cvt8(*(const f4*)p, *(const f4*)(p + 4));
                }
            } else {
                a[mi] = *(const s8v*)&A2h[(size_t)r[mi] * K2 + (ks - KS1) * 32 + q8];
            }
        }
#pragma unroll
        for (int ni = 0; ni < NT; ++ni) {
            const size_t fo = (((size_t)(colTile0 + ni) * KS + ks) << 9) + ((size_t)lane << 3);
            bh[ni] = *(const s8v*)&Wth[fo];
            bl[ni] = *(const s8v*)&Wtl[fo];
        }
    };
    auto MF = [&](const s8v* a, const s8v* bh, const s8v* bl) {
#pragma unroll
        for (int mi = 0; mi < 8; ++mi)
#pragma unroll
            for (int ni = 0; ni < NT; ++ni) {
                acc[mi][ni] = __builtin_amdgcn_mfma_f32_16x16x32_bf16(a[mi], bh[ni], acc[mi][ni], 0, 0, 0);
                acc[mi][ni] = __builtin_amdgcn_mfma_f32_16x16x32_bf16(a[mi], bl[ni], acc[mi][ni], 0, 0, 0);
            }
    };

    LOAD(0, aA, bhA, blA);
#pragma unroll
    for (int ks = 0; ks < KS; ++ks) {
        if ((ks & 1) == 0) {
            if (ks + 1 < KS) LOAD(ks + 1, aB, bhB, blB);
            __builtin_amdgcn_sched_group_barrier(0x20, NLOAD, 0);  // VMEM_READ
            MF(aA, bhA, blA);
            __builtin_amdgcn_sched_group_barrier(0x8, NMFMA, 0);   // MFMA
        } else {
            if (ks + 1 < KS) LOAD(ks + 1, aA, bhA, blA);
            __builtin_amdgcn_sched_group_barrier(0x20, NLOAD, 0);
            MF(aB, bhB, blB);
            __builtin_amdgcn_sched_group_barrier(0x8, NMFMA, 0);
        }
    }

    // ---- epilogue: C/D layout col=lane&15, row=(lane>>4)*4+reg ----
#pragma unroll
    for (int mi = 0; mi < 8; ++mi) {
#pragma unroll
        for (int reg = 0; reg < 4; ++reg) {
            const int row = rbase + mi * 16 + (lane >> 4) * 4 + reg;
            if (row >= M) continue;
            const float rs = SCALE ? rowscale[row] : 1.f;
#pragma unroll
            for (int ni = 0; ni < NT; ++ni) {
                const int col = bn + ni * 16 + c16;
                float v = acc[mi][ni][reg];
                if (SCALE) v *= rs;
                if (bias) v += bias[col];
                if (RELU) v = fmaxf(v, 0.f);
                if constexpr (OUTMODE == 2) {
                    Ch[(size_t)row * Nout + col] = f2bf(v);
                } else if constexpr (OUTMODE == 3) {
                    Cf[(size_t)row * Nout + col] = v;
                    Ch[(size_t)row * Nout + col] = f2bf(v);
                } else {
                    Cf[(size_t)row * Nout + col] = v;
                }
            }
        }
    }
}

// ---------------- weight transpose + split (fragment-major) -----------------
struct WDesc { const float* W; ushort_t* h; ushort_t* l; int K; int No; };
struct WAll { WDesc d[6]; };

__global__ void wtcvt_kernel(WAll wa) {
    WDesc d = wa.d[blockIdx.y];
    int e = blockIdx.x * blockDim.x + threadIdx.x;
    if (e >= d.K * d.No) return;
    int k = e / d.No, n = e - k * d.No;
    ushort_t h, l;
    bsplit(d.W[e], h, l);
    int colTile = n >> 4, c16 = n & 15;
    int ks = k >> 5, quad = (k >> 3) & 3, j = k & 7;
    int lane = c16 + (quad << 4);
    size_t idx = (((size_t)colTile * (d.K >> 5) + ks) << 9) + ((size_t)lane << 3) + j;
    d.h[idx] = h;
    d.l[idx] = l;
}

// ---------------- bucketed CSR build ----------------------------------------
__global__ __launch_bounds__(256) void bcount_kernel(const int* __restrict__ dst,
                                                     int* __restrict__ bcount, int E, int NB) {
    __shared__ int cnt[256];
    const int t = threadIdx.x;
    if (t < NB) cnt[t] = 0;
    __syncthreads();
    for (int e = blockIdx.x * 256 + t; e < E; e += gridDim.x * 256)
        atomicAdd(&cnt[dst[e] >> BSHIFT], 1);
    __syncthreads();
    if (t < NB && cnt[t]) atomicAdd(&bcount[t], cnt[t]);
}

__global__ __launch_bounds__(256) void bscan_kernel(const int* __restrict__ bcount,
                                                    int* __restrict__ bbase,
                                                    int* __restrict__ bcursor, int NB, int E) {
    __shared__ int s[256];
    const int t = threadIdx.x;
    s[t] = (t < NB) ? bcount[t] : 0;
    __syncthreads();
    for (int off = 1; off < 256; off <<= 1) {
        int v = (t >= off) ? s[t - off] : 0;
        __syncthreads();
        s[t] += v;
        __syncthreads();
    }
    int excl = t ? s[t - 1] : 0;
    if (t < NB) { bbase[t] = excl; bcursor[t] = excl; }
    if (t == 0) bbase[NB] = E;
}

__global__ __launch_bounds__(256) void bpart_kernel(const int* __restrict__ src,
                                                    const int* __restrict__ dst,
                                                    int* __restrict__ bcursor,
                                                    unsigned* __restrict__ packed, int E, int NB) {
    __shared__ int cnt[256];
    __shared__ int cur[256];
    const int t = threadIdx.x;
    const int beg = blockIdx.x * 8192;
    const int end = min(beg + 8192, E);
    if (t < NB) cnt[t] = 0;
    __syncthreads();
    for (int e = beg + t; e < end; e += 256) atomicAdd(&cnt[dst[e] >> BSHIFT], 1);
    __syncthreads();
    if (t < NB && cnt[t]) cur[t] = atomicAdd(&bcursor[t], cnt[t]);
    __syncthreads();
    for (int e = beg + t; e < end; e += 256) {
        int d = dst[e];
        int b = d >> BSHIFT;
        int pos = atomicAdd(&cur[b], 1);
        packed[pos] = (unsigned)src[e] | ((unsigned)(d & ((1 << BSHIFT) - 1)) << 16);
    }
}

__global__ __launch_bounds__(256) void bbuild_kernel(const int* __restrict__ bbase,
                                                     const unsigned* __restrict__ packed,
                                                     int* __restrict__ col,
                                                     int* __restrict__ rowstart,
                                                     float* __restrict__ dinv, int N, int E) {
    __shared__ int ncnt[256];
    __shared__ int s[256];
    __shared__ int ncur[256];
    const int b = blockIdx.x;
    const int t = threadIdx.x;
    const int beg = bbase[b], end = bbase[b + 1];
    const int node0 = b << BSHIFT;
    const int nInB = min(256, N - node0);
    ncnt[t] = 0;
    __syncthreads();
    for (int e = beg + t; e < end; e += 256) atomicAdd(&ncnt[packed[e] >> 16], 1);
    __syncthreads();
    s[t] = ncnt[t];
    __syncthreads();
    for (int off = 1; off < 256; off <<= 1) {
        int v = (t >= off) ? s[t - off] : 0;
        __syncthreads();
        s[t] += v;
        __syncthreads();
    }
    int excl = t ? s[t - 1] : 0;
    if (t < nInB) {
        rowstart[node0 + t] = beg + excl;
        dinv[node0 + t] = rsqrtf((float)ncnt[t] + 1.0f);
    }
    ncur[t] = beg + excl;
    __syncthreads();
    for (int e = beg + t; e < end; e += 256) {
        unsigned p = packed[e];
        int pos = atomicAdd(&ncur[p >> 16], 1);
        col[pos] = (int)(p & 0xFFFFu);
    }
    if (b == 0 && t == 0) rowstart[N] = E;
}

// ---------------- CSR gather (bf16 in, bf16 out, 8-deep ILP) ----------------
template <int F>
__global__ __launch_bounds__(256) void gather_bf_kernel(const int* __restrict__ rowstart,
                                                        const int* __restrict__ col,
                                                        const float* __restrict__ dinv,
                                                        const ushort_t* __restrict__ hws,
                                                        const float* __restrict__ bias,
                                                        ushort_t* __restrict__ aggb, int N) {
    const int wave = threadIdx.x >> 6;
    const int lane = threadIdx.x & 63;
    const int d = blockIdx.x * 4 + wave;
    if (d >= N) return;
    const int beg = rowstart[d], end = rowstart[d + 1];
    const float dd = dinv[d];
    if (F == 128) {
        const unsigned* base = (const unsigned*)hws;   // 2 bf16 per uint
        unsigned sv = base[(size_t)d * 64 + lane];
        float ax = __uint_as_float(sv << 16);
        float ay = __uint_as_float(sv & 0xFFFF0000u);
        for (int e0 = beg; e0 < end; e0 += 64) {
            int nid = (e0 + lane < end) ? col[e0 + lane] : 0;
            int cnt = min(64, end - e0);
            int j = 0;
            for (; j + 8 <= cnt; j += 8) {
                unsigned u[8];
#pragma unroll
                for (int q = 0; q < 8; ++q) {
                    int s = __shfl(nid, j + q);
                    u[q] = base[(size_t)s * 64 + lane];
                }
#pragma unroll
                for (int q = 0; q < 8; ++q) {
                    ax += __uint_as_float(u[q] << 16);
                    ay += __uint_as_float(u[q] & 0xFFFF0000u);
                }
            }
            for (; j < cnt; ++j) {
                int s = __shfl(nid, j);
                unsigned uu = base[(size_t)s * 64 + lane];
                ax += __uint_as_float(uu << 16);
                ay += __uint_as_float(uu & 0xFFFF0000u);
            }
        }
        float2 b = ((const float2*)bias)[lane];
        float rx = fmaxf(ax * dd + b.x, 0.f);
        float ry = fmaxf(ay * dd + b.y, 0.f);
        unsigned pk = ((unsigned)f2bf(ry) << 16) | (unsigned)f2bf(rx);
        ((unsigned*)aggb)[(size_t)d * 64 + lane] = pk;
    } else {  // F == 64
        float acc = __uint_as_float((unsigned)hws[(size_t)d * 64 + lane] << 16);
        for (int e0 = beg; e0 < end; e0 += 64) {
            int nid = (e0 + lane < end) ? col[e0 + lane] : 0;
            int cnt = min(64, end - e0);
            int j = 0;
            for (; j + 8 <= cnt; j += 8) {
                ushort_t u[8];
#pragma unroll
                for (int q = 0; q < 8; ++q) {
                    int s = __shfl(nid, j + q);
                    u[q] = hws[(size_t)s * 64 + lane];
                }
#pragma unroll
                for (int q = 0; q < 8; ++q) acc += __uint_as_float((unsigned)u[q] << 16);
            }
            for (; j < cnt; ++j) {
                int s = __shfl(nid, j);
                acc += __uint_as_float((unsigned)hws[(size_t)s * 64 + lane] << 16);
            }
        }
        acc = fmaxf(acc * dd + bias[lane], 0.f);
        aggb[(size_t)d * 64 + lane] = f2bf(acc);
    }
}

// ---------------- edge decode (bf16 emb1 copy) ------------------------------
__global__ __launch_bounds__(256) void decode_kernel(const ushort_t* __restrict__ emb1b,
                                                     const int* __restrict__ eli,
                                                     const float* __restrict__ Wpost,
                                                     const float* __restrict__ bpost,
                                                     float* __restrict__ pred, int L) {
    const int wave = threadIdx.x >> 6;
    const int lane = threadIdx.x & 63;
    const int l = blockIdx.x * 4 + wave;
    if (l >= L) return;
    int s = eli[l];
    int d = eli[L + l];
    float w = Wpost[lane * 2] + Wpost[lane * 2 + 1];
    float a = __uint_as_float((unsigned)emb1b[(size_t)s * 64 + lane] << 16);
    float b = __uint_as_float((unsigned)emb1b[(size_t)d * 64 + lane] << 16);
    float p = a * b * w;
#pragma unroll
    for (int off = 32; off; off >>= 1) p += __shfl_down(p, off);
    if (lane == 0) pred[l] = p + bpost[0] + bpost[1];
}

// ---------------------------------------------------------------------------
extern "C" void kernel_launch(void* const* d_in, const int* in_sizes, int n_in,
                              void* d_out, int out_size, void* d_ws, size_t ws_size,
                              hipStream_t stream) {
    const float* x     = (const float*)d_in[0];
    const float* prev0 = (const float*)d_in[1];
    const float* prev1 = (const float*)d_in[2];
    const float* Wpre1 = (const float*)d_in[3];
    const float* bpre1 = (const float*)d_in[4];
    const float* Wpre2 = (const float*)d_in[5];
    const float* bpre2 = (const float*)d_in[6];
    const float* Wc1   = (const float*)d_in[7];
    const float* bc1   = (const float*)d_in[8];
    const float* Wc2   = (const float*)d_in[9];
    const float* bc2   = (const float*)d_in[10];
    const float* Wm1   = (const float*)d_in[11];
    const float* bm1   = (const float*)d_in[12];
    const float* Wm2   = (const float*)d_in[13];
    const float* bm2   = (const float*)d_in[14];
    const float* Wpost = (const float*)d_in[15];
    const float* bpost = (const float*)d_in[16];
    const int* edge_index = (const int*)d_in[17];
    const int* eli        = (const int*)d_in[18];

    const int N = in_sizes[0] / 256;   // 50000  (must be <= 65536 for packing)
    const int E = in_sizes[17] / 2;    // 1.6M
    const int L = in_sizes[18] / 2;    // 200K
    const int NB = (N + 255) >> BSHIFT;

    const int* src = edge_index;
    const int* dst = edge_index + E;

    float* out  = (float*)d_out;
    float* pred = out;                        // [L]
    float* emb0 = out + L;                    // [N,128]
    float* emb1 = out + L + (size_t)N * 128;  // [N,64]

    // ---- workspace layout (FLOAT-SLOT offsets; sizes verified) ----
    //  region            fl-slots   lifetime
    //  packed  [0,32N)    32N       bpart -> bbuild   (before G1)
    //  h1h     [0,128N)   128N      G1 -> G2          ([N,256]us)
    //  hws1b   [0,64N)    64N       G3 -> gather1     ([N,128]us)
    //  agg1b   [64N,128N) 64N       gather1 -> G5
    //  emb0b   [0,64N)    64N       G5 -> G6
    //  hws2b   [64N,96N)  32N       G6 -> gather2     ([N,64]us)
    //  agg2b   [96N,128N) 32N       gather2 -> G8
    //  emb1b   [0,32N)    32N       G8 -> decode
    //  h2b     [128N,192N) 64N      G2 -> G3          ([N,128]us)
    //  p0b     [192N,256N) 64N      cvt -> G5         ([N,128]us)
    //  p1b     [256N,288N) 32N      cvt -> G8         ([N,64]us)
    //  col     [288N,320N) 32N      build -> end
    //  rowstart/dinv/buckets/wb in tail.  Peak ~325N fl = 65 MB.
    float* ws = (float*)d_ws;
    unsigned* packed = (unsigned*)ws;
    ushort_t* h1h   = (ushort_t*)ws;
    ushort_t* hws1b = (ushort_t*)ws;
    ushort_t* emb0b = (ushort_t*)ws;
    ushort_t* emb1b = (ushort_t*)ws;
    ushort_t* agg1b = (ushort_t*)(ws + (size_t)64 * N);
    ushort_t* hws2b = (ushort_t*)(ws + (size_t)64 * N);
    ushort_t* agg2b = (ushort_t*)(ws + (size_t)96 * N);
    ushort_t* h2b   = (ushort_t*)(ws + (size_t)128 * N);
    ushort_t* p0b   = (ushort_t*)(ws + (size_t)192 * N);
    ushort_t* p1b   = (ushort_t*)(ws + (size_t)256 * N);
    int*      col   = (int*)(ws + (size_t)288 * N);

    size_t o = (size_t)320 * N;
    int* rowstart = (int*)(ws + o);         o += ((size_t)N + 4) & ~(size_t)3;
    float* dinv = ws + o;                   o += ((size_t)N + 3) & ~(size_t)3;
    int* bbase = (int*)(ws + o);            o += 260;
    int* bcursor = (int*)(ws + o);          o += 260;
    int* bcount = (int*)(ws + o);           o += 260;
    ushort_t* wb = (ushort_t*)(ws + o);     // 327680 ushorts (16B-aligned)

    ushort_t* wpre1h = wb + 0;       ushort_t* wpre1l = wb + 65536;
    ushort_t* wpre2h = wb + 131072;  ushort_t* wpre2l = wb + 163840;
    ushort_t* wc1h   = wb + 196608;  ushort_t* wc1l   = wb + 212992;
    ushort_t* wm1h   = wb + 229376;  ushort_t* wm1l   = wb + 262144;
    ushort_t* wc2h   = wb + 294912;  ushort_t* wc2l   = wb + 303104;
    ushort_t* wm2h   = wb + 311296;  ushort_t* wm2l   = wb + 319488;

    // 0) prev0/prev1 -> bf16 (disjoint regions; before anything reads them)
    {
        size_t n0 = (size_t)N * 128, n1 = (size_t)N * 64;
        f2b_kernel<<<(int)((n0 / 8 + 255) / 256), 256, 0, stream>>>(prev0, p0b, n0);
        f2b_kernel<<<(int)((n1 / 8 + 255) / 256), 256, 0, stream>>>(prev1, p1b, n1);
    }

    // 0a) bucketed CSR build + dinv (packed aliases h1h region; done pre-G1)
    hipMemsetAsync(bcount, 0, (size_t)NB * sizeof(int), stream);
    bcount_kernel<<<1024, 256, 0, stream>>>(dst, bcount, E, NB);
    bscan_kernel<<<1, 256, 0, stream>>>(bcount, bbase, bcursor, NB, E);
    bpart_kernel<<<(E + 8191) / 8192, 256, 0, stream>>>(src, dst, bcursor, packed, E, NB);
    bbuild_kernel<<<NB, 256, 0, stream>>>(bbase, packed, col, rowstart, dinv, N, E);

    // 0b) weights: transpose + hi/lo split into fragment-major layout
    WAll wa;
    wa.d[0] = {Wpre1, wpre1h, wpre1l, 256, 256};
    wa.d[1] = {Wpre2, wpre2h, wpre2l, 256, 128};
    wa.d[2] = {Wc1,   wc1h,   wc1l,   128, 128};
    wa.d[3] = {Wm1,   wm1h,   wm1l,   256, 128};
    wa.d[4] = {Wc2,   wc2h,   wc2l,   128, 64};
    wa.d[5] = {Wm2,   wm2h,   wm2l,   128, 64};
    wtcvt_kernel<<<dim3(256, 6), 256, 0, stream>>>(wa);

    const int gy = (N + 127) / 128;   // 391 row blocks

    // 1) h1 = bf16(relu(x@Wpre1+b))           [N,256]  K=256, fp32 A
    gemm_wide<2, 8, 0, false, true, false, 2><<<dim3(2, gy), 256, 0, stream>>>(
        x, nullptr, nullptr, wpre1h, wpre1l, bpre1, nullptr, nullptr, h1h, N, 256);
    // 2) h2 = bf16(relu(h1@Wpre2+b))          [N,128]  K=256, bf16 A
    gemm_wide<2, 8, 0, true, true, false, 2><<<dim3(1, gy), 256, 0, stream>>>(
        nullptr, h1h, nullptr, wpre2h, wpre2l, bpre2, nullptr, nullptr, h2b, N, 128);
    // 3) hws1 = bf16((h2@Wc1)*dinv[row])      [N,128]  K=128  (h1 dead)
    gemm_wide<2, 4, 0, true, false, true, 2><<<dim3(1, gy), 256, 0, stream>>>(
        nullptr, h2b, nullptr, wc1h, wc1l, nullptr, dinv, nullptr, hws1b, N, 128);
    // 4) agg1 = bf16(relu(dinv*(hws1[d]+sum hws1[s])+bc1))
    gather_bf_kernel<128><<<(N + 3) / 4, 256, 0, stream>>>(rowstart, col, dinv, hws1b, bc1, agg1b, N);
    // 5) emb0 = [agg1,prev0]@Wm1+bm1 (fp32 + bf16 copy)  [N,128]  K=128+128
    gemm_wide<2, 4, 4, true, false, false, 3><<<dim3(1, gy), 256, 0, stream>>>(
        nullptr, agg1b, p0b, wm1h, wm1l, bm1, nullptr, emb0, emb0b, N, 128);
    // 6) hws2 = bf16((emb0@Wc2)*dinv[row])    [N,64]   K=128, bf16 A
    gemm_wide<1, 4, 0, true, false, true, 2><<<dim3(1, gy), 256, 0, stream>>>(
        nullptr, emb0b, nullptr, wc2h, wc2l, nullptr, dinv, nullptr, hws2b, N, 64);
    // 7) agg2 = bf16(relu(dinv*(hws2[d]+sum hws2[s])+bc2))
    gather_bf_kernel<64><<<(N + 3) / 4, 256, 0, stream>>>(rowstart, col, dinv, hws2b, bc2, agg2b, N);
    // 8) emb1 = [agg2,prev1]@Wm2+bm2 (fp32 + bf16 copy)  [N,64]  K=64+64
    gemm_wide<1, 2, 2, true, false, false, 3><<<dim3(1, gy), 256, 0, stream>>>(
        nullptr, agg2b, p1b, wm2h, wm2l, bm2, nullptr, emb1, emb1b, N, 64);
    // 9) decode (bf16 emb1 copy, L2-resident)
    decode_kernel<<<(L + 3) / 4, 256, 0, stream>>>(emb1b, eli, Wpost, bpost, pred, L);
}

// Round 16
// 352.872 us; speedup vs baseline: 1.3109x; 1.1899x over previous
//
#include <hip/hip_runtime.h>
#include <hip/hip_bf16.h>

// ---------------------------------------------------------------------------
// ROLAND-style GNN forward. Round 15: revert to the best-measured structure
// (R12 gemm_reg, frag-major weights, register-only streaming) and switch to
// SINGLE-PASS bf16 weights: per-k-step load count -33..40% and MFMA count
// halved (loads are the measured cost driver: hipcc serializes to ~1 load in
// flight; R6-R15 all hit the same ~0.9 TB/s wall). Error budget: bf16-weight
// noise ~ bf16-activation noise -> absmax ~0.045-0.06 < 0.095.
// Bucketed CSR build; bf16 CSR gather with 8-deep ILP; bf16 decode.
// ---------------------------------------------------------------------------

typedef unsigned short ushort_t;
typedef __attribute__((ext_vector_type(8))) short s8v;   // 8 bf16 (4 VGPRs)
typedef __attribute__((ext_vector_type(4))) float f4;    // MFMA accumulator

#define BSHIFT 8                       // nodes per bucket = 256 (N<=65536)

__device__ __forceinline__ ushort_t f2bf(float v) {
    unsigned u = __float_as_uint(v);
    return (ushort_t)((u + 0x7FFFu + ((u >> 16) & 1u)) >> 16);
}

__device__ __forceinline__ s8v cvt8(f4 v0, f4 v1) {
    ushort_t hb[8];
    hb[0] = f2bf(v0.x); hb[1] = f2bf(v0.y); hb[2] = f2bf(v0.z); hb[3] = f2bf(v0.w);
    hb[4] = f2bf(v1.x); hb[5] = f2bf(v1.y); hb[6] = f2bf(v1.z); hb[7] = f2bf(v1.w);
    return *(s8v*)hb;
}

// ---------------- register-only streaming MFMA GEMM (single-pass bf16 W) ----
// C[M,Nout] = epilogue( A[M,K1] (++ A2[M,KW-K1]) @ W[KW,Nout] )
// grid.x = ceil(M/32); block = 4 waves, wave w = column panel w (NT*16 cols).
// Wth is FRAGMENT-MAJOR: ((colTile*(KW/32)+ks)*64+lane)*8+j.
// A1BF: A1 is bf16. OUTMODE: 0 = fp32, 2 = bf16, 3 = fp32 + bf16 copy.
template <int NT, int KW, int K1, bool RELU, bool SCALE, bool DUAL, bool A1BF, int OUTMODE>
__global__ __launch_bounds__(256, 3) void gemm_reg(
    const float* __restrict__ A1f, const ushort_t* __restrict__ A1h,
    const float* __restrict__ A2f,
    const ushort_t* __restrict__ Wth,
    const float* __restrict__ bias, const float* __restrict__ rowscale,
    float* __restrict__ Cf, ushort_t* __restrict__ Ch,
    int M, int Nout)
{
    constexpr int K2 = KW - K1;
    constexpr int KS = KW / 32;            // k-steps
    const int lane  = threadIdx.x & 63;
    const int w     = threadIdx.x >> 6;
    const int rbase = blockIdx.x * 32;
    const int bn    = w * (NT * 16);
    if (rbase >= M) return;

    f4 acc[2][NT];
    const f4 zero = {0.f, 0.f, 0.f, 0.f};
#pragma unroll
    for (int mi = 0; mi < 2; ++mi)
#pragma unroll
        for (int ni = 0; ni < NT; ++ni) acc[mi][ni] = zero;

    const int r0 = min(rbase + (lane & 15), M - 1);
    const int r1 = min(rbase + 16 + (lane & 15), M - 1);
    const int kq = (lane >> 4) * 8;        // k-offset of this lane's 8 elems

    // two named register sets
    s8v a0A, a1A, bhA[NT];
    s8v a0B, a1B, bhB[NT];

    auto loadK = [&](int ks, s8v& a0, s8v& a1, s8v* bh) {
        const int kb = ks * 32 + kq;
        if (DUAL && ks * 32 >= K1) {
            const float* p0 = &A2f[(size_t)r0 * K2 + (kb - K1)];
            const float* p1 = &A2f[(size_t)r1 * K2 + (kb - K1)];
            a0 = cvt8(*(const f4*)p0, *(const f4*)(p0 + 4));
            a1 = cvt8(*(const f4*)p1, *(const f4*)(p1 + 4));
        } else if (A1BF) {
            a0 = *(const s8v*)&A1h[(size_t)r0 * K1 + kb];
            a1 = *(const s8v*)&A1h[(size_t)r1 * K1 + kb];
        } else {
            const float* p0 = &A1f[(size_t)r0 * K1 + kb];
            const float* p1 = &A1f[(size_t)r1 * K1 + kb];
            a0 = cvt8(*(const f4*)p0, *(const f4*)(p0 + 4));
            a1 = cvt8(*(const f4*)p1, *(const f4*)(p1 + 4));
        }
#pragma unroll
        for (int ni = 0; ni < NT; ++ni) {
            const size_t fo = (((size_t)((bn >> 4) + ni) * KS + ks) << 9) + ((size_t)lane << 3);
            bh[ni] = *(const s8v*)&Wth[fo];
        }
    };
    auto mfmaK = [&](const s8v& a0, const s8v& a1, const s8v* bh) {
#pragma unroll
        for (int ni = 0; ni < NT; ++ni) {
            acc[0][ni] = __builtin_amdgcn_mfma_f32_16x16x32_bf16(a0, bh[ni], acc[0][ni], 0, 0, 0);
            acc[1][ni] = __builtin_amdgcn_mfma_f32_16x16x32_bf16(a1, bh[ni], acc[1][ni], 0, 0, 0);
        }
    };

    loadK(0, a0A, a1A, bhA);
#pragma unroll
    for (int ks = 0; ks < KS; ++ks) {
        if ((ks & 1) == 0) {
            if (ks + 1 < KS) loadK(ks + 1, a0B, a1B, bhB);
            mfmaK(a0A, a1A, bhA);
        } else {
            if (ks + 1 < KS) loadK(ks + 1, a0A, a1A, bhA);
            mfmaK(a0B, a1B, bhB);
        }
    }

    // ---- epilogue: C/D layout col=lane&15, row=(lane>>4)*4+reg ----
#pragma unroll
    for (int mi = 0; mi < 2; ++mi) {
#pragma unroll
        for (int reg = 0; reg < 4; ++reg) {
            const int row = rbase + mi * 16 + (lane >> 4) * 4 + reg;
            if (row >= M) continue;
            const float rs = SCALE ? rowscale[row] : 1.f;
#pragma unroll
            for (int ni = 0; ni < NT; ++ni) {
                const int col = bn + ni * 16 + (lane & 15);
                float v = acc[mi][ni][reg];
                if (SCALE) v *= rs;
                if (bias) v += bias[col];
                if (RELU) v = fmaxf(v, 0.f);
                if constexpr (OUTMODE == 2) {
                    Ch[(size_t)row * Nout + col] = f2bf(v);
                } else if constexpr (OUTMODE == 3) {
                    Cf[(size_t)row * Nout + col] = v;
                    Ch[(size_t)row * Nout + col] = f2bf(v);
                } else {
                    Cf[(size_t)row * Nout + col] = v;
                }
            }
        }
    }
}

// ---------------- weight transpose + bf16 convert (fragment-major) ----------
struct WDesc { const float* W; ushort_t* h; int K; int No; };
struct WAll { WDesc d[6]; };

__global__ void wtcvt_kernel(WAll wa) {
    WDesc d = wa.d[blockIdx.y];
    int e = blockIdx.x * blockDim.x + threadIdx.x;
    if (e >= d.K * d.No) return;
    int k = e / d.No, n = e - k * d.No;
    int colTile = n >> 4, c16 = n & 15;
    int ks = k >> 5, quad = (k >> 3) & 3, j = k & 7;
    int lane = c16 + (quad << 4);
    size_t idx = (((size_t)colTile * (d.K >> 5) + ks) << 9) + ((size_t)lane << 3) + j;
    d.h[idx] = f2bf(d.W[e]);
}

// ---------------- bucketed CSR build ----------------------------------------
__global__ __launch_bounds__(256) void bcount_kernel(const int* __restrict__ dst,
                                                     int* __restrict__ bcount, int E, int NB) {
    __shared__ int cnt[256];
    const int t = threadIdx.x;
    if (t < NB) cnt[t] = 0;
    __syncthreads();
    for (int e = blockIdx.x * 256 + t; e < E; e += gridDim.x * 256)
        atomicAdd(&cnt[dst[e] >> BSHIFT], 1);
    __syncthreads();
    if (t < NB && cnt[t]) atomicAdd(&bcount[t], cnt[t]);
}

__global__ __launch_bounds__(256) void bscan_kernel(const int* __restrict__ bcount,
                                                    int* __restrict__ bbase,
                                                    int* __restrict__ bcursor, int NB, int E) {
    __shared__ int s[256];
    const int t = threadIdx.x;
    s[t] = (t < NB) ? bcount[t] : 0;
    __syncthreads();
    for (int off = 1; off < 256; off <<= 1) {
        int v = (t >= off) ? s[t - off] : 0;
        __syncthreads();
        s[t] += v;
        __syncthreads();
    }
    int excl = t ? s[t - 1] : 0;
    if (t < NB) { bbase[t] = excl; bcursor[t] = excl; }
    if (t == 0) bbase[NB] = E;
}

__global__ __launch_bounds__(256) void bpart_kernel(const int* __restrict__ src,
                                                    const int* __restrict__ dst,
                                                    int* __restrict__ bcursor,
                                                    unsigned* __restrict__ packed, int E, int NB) {
    __shared__ int cnt[256];
    __shared__ int cur[256];
    const int t = threadIdx.x;
    const int beg = blockIdx.x * 8192;
    const int end = min(beg + 8192, E);
    if (t < NB) cnt[t] = 0;
    __syncthreads();
    for (int e = beg + t; e < end; e += 256) atomicAdd(&cnt[dst[e] >> BSHIFT], 1);
    __syncthreads();
    if (t < NB && cnt[t]) cur[t] = atomicAdd(&bcursor[t], cnt[t]);
    __syncthreads();
    for (int e = beg + t; e < end; e += 256) {
        int d = dst[e];
        int b = d >> BSHIFT;
        int pos = atomicAdd(&cur[b], 1);
        packed[pos] = (unsigned)src[e] | ((unsigned)(d & ((1 << BSHIFT) - 1)) << 16);
    }
}

__global__ __launch_bounds__(256) void bbuild_kernel(const int* __restrict__ bbase,
                                                     const unsigned* __restrict__ packed,
                                                     int* __restrict__ col,
                                                     int* __restrict__ rowstart,
                                                     float* __restrict__ dinv, int N, int E) {
    __shared__ int ncnt[256];
    __shared__ int s[256];
    __shared__ int ncur[256];
    const int b = blockIdx.x;
    const int t = threadIdx.x;
    const int beg = bbase[b], end = bbase[b + 1];
    const int node0 = b << BSHIFT;
    const int nInB = min(256, N - node0);
    ncnt[t] = 0;
    __syncthreads();
    for (int e = beg + t; e < end; e += 256) atomicAdd(&ncnt[packed[e] >> 16], 1);
    __syncthreads();
    s[t] = ncnt[t];
    __syncthreads();
    for (int off = 1; off < 256; off <<= 1) {
        int v = (t >= off) ? s[t - off] : 0;
        __syncthreads();
        s[t] += v;
        __syncthreads();
    }
    int excl = t ? s[t - 1] : 0;
    if (t < nInB) {
        rowstart[node0 + t] = beg + excl;
        dinv[node0 + t] = rsqrtf((float)ncnt[t] + 1.0f);
    }
    ncur[t] = beg + excl;
    __syncthreads();
    for (int e = beg + t; e < end; e += 256) {
        unsigned p = packed[e];
        int pos = atomicAdd(&ncur[p >> 16], 1);
        col[pos] = (int)(p & 0xFFFFu);
    }
    if (b == 0 && t == 0) rowstart[N] = E;
}

// ---------------- CSR gather (bf16 in, bf16 out, 8-deep ILP) ----------------
template <int F>
__global__ __launch_bounds__(256) void gather_bf_kernel(const int* __restrict__ rowstart,
                                                        const int* __restrict__ col,
                                                        const float* __restrict__ dinv,
                                                        const ushort_t* __restrict__ hws,
                                                        const float* __restrict__ bias,
                                                        ushort_t* __restrict__ aggb, int N) {
    const int wave = threadIdx.x >> 6;
    const int lane = threadIdx.x & 63;
    const int d = blockIdx.x * 4 + wave;
    if (d >= N) return;
    const int beg = rowstart[d], end = rowstart[d + 1];
    const float dd = dinv[d];
    if (F == 128) {
        const unsigned* base = (const unsigned*)hws;   // 2 bf16 per uint
        unsigned sv = base[(size_t)d * 64 + lane];
        float ax = __uint_as_float(sv << 16);
        float ay = __uint_as_float(sv & 0xFFFF0000u);
        for (int e0 = beg; e0 < end; e0 += 64) {
            int nid = (e0 + lane < end) ? col[e0 + lane] : 0;
            int cnt = min(64, end - e0);
            int j = 0;
            for (; j + 8 <= cnt; j += 8) {
                unsigned u[8];
#pragma unroll
                for (int q = 0; q < 8; ++q) {
                    int s = __shfl(nid, j + q);
                    u[q] = base[(size_t)s * 64 + lane];
                }
#pragma unroll
                for (int q = 0; q < 8; ++q) {
                    ax += __uint_as_float(u[q] << 16);
                    ay += __uint_as_float(u[q] & 0xFFFF0000u);
                }
            }
            for (; j < cnt; ++j) {
                int s = __shfl(nid, j);
                unsigned uu = base[(size_t)s * 64 + lane];
                ax += __uint_as_float(uu << 16);
                ay += __uint_as_float(uu & 0xFFFF0000u);
            }
        }
        float2 b = ((const float2*)bias)[lane];
        float rx = fmaxf(ax * dd + b.x, 0.f);
        float ry = fmaxf(ay * dd + b.y, 0.f);
        unsigned pk = ((unsigned)f2bf(ry) << 16) | (unsigned)f2bf(rx);
        ((unsigned*)aggb)[(size_t)d * 64 + lane] = pk;
    } else {  // F == 64
        float acc = __uint_as_float((unsigned)hws[(size_t)d * 64 + lane] << 16);
        for (int e0 = beg; e0 < end; e0 += 64) {
            int nid = (e0 + lane < end) ? col[e0 + lane] : 0;
            int cnt = min(64, end - e0);
            int j = 0;
            for (; j + 8 <= cnt; j += 8) {
                ushort_t u[8];
#pragma unroll
                for (int q = 0; q < 8; ++q) {
                    int s = __shfl(nid, j + q);
                    u[q] = hws[(size_t)s * 64 + lane];
                }
#pragma unroll
                for (int q = 0; q < 8; ++q) acc += __uint_as_float((unsigned)u[q] << 16);
            }
            for (; j < cnt; ++j) {
                int s = __shfl(nid, j);
                acc += __uint_as_float((unsigned)hws[(size_t)s * 64 + lane] << 16);
            }
        }
        acc = fmaxf(acc * dd + bias[lane], 0.f);
        aggb[(size_t)d * 64 + lane] = f2bf(acc);
    }
}

// ---------------- edge decode (bf16 emb1 copy) ------------------------------
__global__ __launch_bounds__(256) void decode_kernel(const ushort_t* __restrict__ emb1b,
                                                     const int* __restrict__ eli,
                                                     const float* __restrict__ Wpost,
                                                     const float* __restrict__ bpost,
                                                     float* __restrict__ pred, int L) {
    const int wave = threadIdx.x >> 6;
    const int lane = threadIdx.x & 63;
    const int l = blockIdx.x * 4 + wave;
    if (l >= L) return;
    int s = eli[l];
    int d = eli[L + l];
    float w = Wpost[lane * 2] + Wpost[lane * 2 + 1];
    float a = __uint_as_float((unsigned)emb1b[(size_t)s * 64 + lane] << 16);
    float b = __uint_as_float((unsigned)emb1b[(size_t)d * 64 + lane] << 16);
    float p = a * b * w;
#pragma unroll
    for (int off = 32; off; off >>= 1) p += __shfl_down(p, off);
    if (lane == 0) pred[l] = p + bpost[0] + bpost[1];
}

// ---------------------------------------------------------------------------
extern "C" void kernel_launch(void* const* d_in, const int* in_sizes, int n_in,
                              void* d_out, int out_size, void* d_ws, size_t ws_size,
                              hipStream_t stream) {
    const float* x     = (const float*)d_in[0];
    const float* prev0 = (const float*)d_in[1];
    const float* prev1 = (const float*)d_in[2];
    const float* Wpre1 = (const float*)d_in[3];
    const float* bpre1 = (const float*)d_in[4];
    const float* Wpre2 = (const float*)d_in[5];
    const float* bpre2 = (const float*)d_in[6];
    const float* Wc1   = (const float*)d_in[7];
    const float* bc1   = (const float*)d_in[8];
    const float* Wc2   = (const float*)d_in[9];
    const float* bc2   = (const float*)d_in[10];
    const float* Wm1   = (const float*)d_in[11];
    const float* bm1   = (const float*)d_in[12];
    const float* Wm2   = (const float*)d_in[13];
    const float* bm2   = (const float*)d_in[14];
    const float* Wpost = (const float*)d_in[15];
    const float* bpost = (const float*)d_in[16];
    const int* edge_index = (const int*)d_in[17];
    const int* eli        = (const int*)d_in[18];

    const int N = in_sizes[0] / 256;   // 50000  (must be <= 65536 for packing)
    const int E = in_sizes[17] / 2;    // 1.6M
    const int L = in_sizes[18] / 2;    // 200K
    const int NB = (N + 255) >> BSHIFT;

    const int* src = edge_index;
    const int* dst = edge_index + E;

    float* out  = (float*)d_out;
    float* pred = out;                        // [L]
    float* emb0 = out + L;                    // [N,128]
    float* emb1 = out + L + (size_t)N * 128;  // [N,64]

    // ---- workspace layout (float slots); identical to R12 (verified) ----
    float* ws = (float*)d_ws;
    ushort_t* h1h   = (ushort_t*)ws;                       // [0,128N)
    ushort_t* hws1b = (ushort_t*)ws;                       // [0,64N)
    ushort_t* emb0b = (ushort_t*)ws;                       // [0,64N)
    ushort_t* emb1b = (ushort_t*)ws;                       // [0,32N)
    ushort_t* agg1b = (ushort_t*)(ws + (size_t)64 * N);    // [64N,128N)
    ushort_t* hws2b = (ushort_t*)(ws + (size_t)64 * N);    // [64N,96N)
    ushort_t* agg2b = (ushort_t*)(ws + (size_t)96 * N);    // [96N,128N)
    ushort_t* h2b   = (ushort_t*)(ws + (size_t)128 * N);   // [128N,192N)

    size_t o = (size_t)192 * N;
    unsigned* packed = (unsigned*)(ws + o); o += ((size_t)E + 3) & ~(size_t)3;
    int* col = (int*)(ws + o);              o += ((size_t)E + 3) & ~(size_t)3;
    int* rowstart = (int*)(ws + o);         o += ((size_t)N + 4) & ~(size_t)3;
    float* dinv = ws + o;                   o += ((size_t)N + 3) & ~(size_t)3;
    int* bbase = (int*)(ws + o);            o += 260;
    int* bcursor = (int*)(ws + o);          o += 260;
    int* bcount = (int*)(ws + o);           o += 260;
    ushort_t* wb = (ushort_t*)(ws + o);     // 163840 ushorts (16B-aligned)

    // single-pass bf16 weight offsets (ushorts) within wb
    ushort_t* wpre1h = wb + 0;        // 256*256 = 65536
    ushort_t* wpre2h = wb + 65536;    // 256*128 = 32768
    ushort_t* wc1h   = wb + 98304;    // 128*128 = 16384
    ushort_t* wm1h   = wb + 114688;   // 256*128 = 32768
    ushort_t* wc2h   = wb + 147456;   // 128*64  = 8192
    ushort_t* wm2h   = wb + 155648;   // 128*64  = 8192

    // 0) bucketed CSR build + dinv
    hipMemsetAsync(bcount, 0, (size_t)NB * sizeof(int), stream);
    bcount_kernel<<<1024, 256, 0, stream>>>(dst, bcount, E, NB);
    bscan_kernel<<<1, 256, 0, stream>>>(bcount, bbase, bcursor, NB, E);
    bpart_kernel<<<(E + 8191) / 8192, 256, 0, stream>>>(src, dst, bcursor, packed, E, NB);
    bbuild_kernel<<<NB, 256, 0, stream>>>(bbase, packed, col, rowstart, dinv, N, E);

    // 0b) weights: transpose + bf16 convert into fragment-major layout
    WAll wa;
    wa.d[0] = {Wpre1, wpre1h, 256, 256};
    wa.d[1] = {Wpre2, wpre2h, 256, 128};
    wa.d[2] = {Wc1,   wc1h,   128, 128};
    wa.d[3] = {Wm1,   wm1h,   256, 128};
    wa.d[4] = {Wc2,   wc2h,   128, 64};
    wa.d[5] = {Wm2,   wm2h,   128, 64};
    wtcvt_kernel<<<dim3(256, 6), 256, 0, stream>>>(wa);

    const int gt = (N + 31) / 32;   // 1563 row-tiles

    // 1) h1 = bf16(relu(x@Wpre1+b))           [N,256]  K=256, fp32 A
    gemm_reg<4, 256, 256, true, false, false, false, 2><<<gt, 256, 0, stream>>>(
        x, nullptr, nullptr, wpre1h, bpre1, nullptr, nullptr, h1h, N, 256);
    // 2) h2 = bf16(relu(h1@Wpre2+b))          [N,128]  K=256, bf16 A
    gemm_reg<2, 256, 256, true, false, false, true, 2><<<gt, 256, 0, stream>>>(
        nullptr, h1h, nullptr, wpre2h, bpre2, nullptr, nullptr, h2b, N, 128);
    // 3) hws1 = bf16((h2@Wc1)*dinv[row])      [N,128]  K=128  (h1 dead)
    gemm_reg<2, 128, 128, false, true, false, true, 2><<<gt, 256, 0, stream>>>(
        nullptr, h2b, nullptr, wc1h, nullptr, dinv, nullptr, hws1b, N, 128);
    // 4) agg1 = bf16(relu(dinv*(hws1[d]+sum hws1[s])+bc1))
    gather_bf_kernel<128><<<(N + 3) / 4, 256, 0, stream>>>(rowstart, col, dinv, hws1b, bc1, agg1b, N);
    // 5) emb0 = [agg1,prev0]@Wm1+bm1 (fp32 + bf16 copy)  [N,128]  K=128+128
    gemm_reg<2, 256, 128, false, false, true, true, 3><<<gt, 256, 0, stream>>>(
        nullptr, agg1b, prev0, wm1h, bm1, nullptr, emb0, emb0b, N, 128);
    // 6) hws2 = bf16((emb0@Wc2)*dinv[row])    [N,64]   K=128, bf16 A
    gemm_reg<1, 128, 128, false, true, false, true, 2><<<gt, 256, 0, stream>>>(
        nullptr, emb0b, nullptr, wc2h, nullptr, dinv, nullptr, hws2b, N, 64);
    // 7) agg2 = bf16(relu(dinv*(hws2[d]+sum hws2[s])+bc2))
    gather_bf_kernel<64><<<(N + 3) / 4, 256, 0, stream>>>(rowstart, col, dinv, hws2b, bc2, agg2b, N);
    // 8) emb1 = [agg2,prev1]@Wm2+bm2 (fp32 + bf16 copy)  [N,64]  K=64+64
    gemm_reg<1, 128, 64, false, false, true, true, 3><<<gt, 256, 0, stream>>>(
        nullptr, agg2b, prev1, wm2h, bm2, nullptr, emb1, emb1b, N, 64);
    // 9) decode (bf16 emb1 copy, L2-resident)
    decode_kernel<<<(L + 3) / 4, 256, 0, stream>>>(emb1b, eli, Wpost, bpost, pred, L);
}

// Round 17
// 327.468 us; speedup vs baseline: 1.4126x; 1.0776x over previous
//
#include <hip/hip_runtime.h>
#include <hip/hip_bf16.h>

// ---------------------------------------------------------------------------
// ROLAND-style GNN forward. Round 16: global_load_lds GEMM (m97 pattern).
// R12-R16 proved the register-path GEMMs are pinned at ~890 GB/s by the
// serial load->wait->use chain per k-step (halving loads AND MFMAs changed
// nothing). gemm_lds stages A and B tiles into LDS via async DMA
// (__builtin_amdgcn_global_load_lds, 16B) -- no VGPR round trip, latency
// drained once per K-iter at the barrier and covered by co-resident blocks.
// BM=128, BN=128/64, 4 waves, BK=64, single-buffered (2 barriers/K-iter).
// G1 reg-stages fp32 x with inline cvt. Weights: plain-transposed bf16.
// Bucketed CSR build; bf16 CSR gather with 8-deep ILP; bf16 decode.
// ---------------------------------------------------------------------------

typedef unsigned short ushort_t;
typedef __attribute__((ext_vector_type(8))) short s8v;   // 8 bf16 (4 VGPRs)
typedef __attribute__((ext_vector_type(4))) float f4;    // MFMA accumulator

#define BSHIFT 8                       // nodes per bucket = 256 (N<=65536)

__device__ __forceinline__ ushort_t f2bf(float v) {
    unsigned u = __float_as_uint(v);
    return (ushort_t)((u + 0x7FFFu + ((u >> 16) & 1u)) >> 16);
}

__device__ __forceinline__ s8v cvt8(f4 v0, f4 v1) {
    ushort_t hb[8];
    hb[0] = f2bf(v0.x); hb[1] = f2bf(v0.y); hb[2] = f2bf(v0.z); hb[3] = f2bf(v0.w);
    hb[4] = f2bf(v1.x); hb[5] = f2bf(v1.y); hb[6] = f2bf(v1.z); hb[7] = f2bf(v1.w);
    return *(s8v*)hb;
}

// async 16B/lane global->LDS DMA; lds base must be wave-uniform
__device__ __forceinline__ void dma16(const ushort_t* g, ushort_t* l) {
    __builtin_amdgcn_global_load_lds(
        (const __attribute__((address_space(1))) unsigned int*)g,
        (__attribute__((address_space(3))) unsigned int*)l, 16, 0, 0);
}

// ---------------- fp32 -> bf16 bulk convert ---------------------------------
__global__ __launch_bounds__(256) void f2b_kernel(const float* __restrict__ in,
                                                  ushort_t* __restrict__ out, size_t n) {
    size_t i = ((size_t)blockIdx.x * 256 + threadIdx.x) * 8;
    if (i + 8 > n) return;
    f4 v0 = *(const f4*)&in[i];
    f4 v1 = *(const f4*)&in[i + 4];
    *(s8v*)&out[i] = cvt8(v0, v1);
}

// ---------------- LDS-staged MFMA GEMM (global_load_lds) --------------------
// C[M,Nout] = epilogue( A1[M,K1] (++ A2[M,KW-K1]) @ W[KW,Nout] )
// grid = (Nout/BN, ceil(M/128)); block = 256 thr = 4 waves (2x2);
// wave tile 64 x (BN/2). Wt: [Nout][KW] bf16 row-major (transposed).
// A1F32: A1 is fp32, reg-staged+cvt (else bf16 via DMA).
// OUTMODE: 0 fp32, 2 bf16, 3 fp32 + bf16 copy.
template <int BN, int KW, int K1, bool A1F32, bool RELU, bool SCALE, bool DUAL, int OUTMODE>
__global__ __launch_bounds__(256, 2) void gemm_lds(
    const float* __restrict__ A1f, const ushort_t* __restrict__ A1h,
    const ushort_t* __restrict__ A2h,
    const ushort_t* __restrict__ Wt,
    const float* __restrict__ bias, const float* __restrict__ rowscale,
    float* __restrict__ Cf, ushort_t* __restrict__ Ch,
    int M, int Nout)
{
    constexpr int NT = BN / 32;            // col tiles per wave
    constexpr int K2 = KW - K1;
    __shared__ ushort_t Abuf[128 * 64];    // [row][k] bf16, 128B rows
    __shared__ ushort_t Bbuf[BN * 64];     // [col][k] bf16, 128B rows

    const int tid  = threadIdx.x;
    const int lane = tid & 63;
    const int w    = tid >> 6;
    const int wr   = w >> 1, wc = w & 1;
    const int rbase = blockIdx.y * 128;
    const int bn    = blockIdx.x * BN;

    f4 acc[4][NT];
    const f4 zero = {0.f, 0.f, 0.f, 0.f};
#pragma unroll
    for (int mi = 0; mi < 4; ++mi)
#pragma unroll
        for (int ni = 0; ni < NT; ++ni) acc[mi][ni] = zero;

    for (int kt = 0; kt < KW; kt += 64) {
        // ---- stage A tile (128 rows x 64 k) ----
        if constexpr (A1F32) {
#pragma unroll
            for (int j = 0; j < 4; ++j) {
                const int c2 = tid + j * 256;          // 0..1023 16B-chunks
                const int row = c2 >> 3, c = c2 & 7;
                const int gr = min(rbase + row, M - 1);
                const float* p = &A1f[(size_t)gr * K1 + kt + c * 8];
                *(s8v*)&Abuf[row * 64 + c * 8] = cvt8(*(const f4*)p, *(const f4*)(p + 4));
            }
        } else {
#pragma unroll
            for (int i = 0; i < 4; ++i) {
                const int s = w * 4 + i;               // 1KB slab id (8 rows)
                const int row = s * 8 + (lane >> 3);
                const int c = lane & 7;
                const int gr = min(rbase + row, M - 1);
                const ushort_t* g;
                if (DUAL && kt >= K1) g = &A2h[(size_t)gr * K2 + (kt - K1) + c * 8];
                else                  g = &A1h[(size_t)gr * K1 + kt + c * 8];
                dma16(g, &Abuf[s * 512]);
            }
        }
        // ---- stage B tile (BN cols x 64 k) ----
#pragma unroll
        for (int i = 0; i < NT; ++i) {
            const int s = w * NT + i;                  // 1KB slab id (8 cols)
            const int colr = s * 8 + (lane >> 3);
            const int c = lane & 7;
            const ushort_t* g = &Wt[(size_t)(bn + colr) * KW + kt + c * 8];
            dma16(g, &Bbuf[s * 512]);
        }
        __syncthreads();                               // drains vmcnt+lgkmcnt
        // ---- compute: 2 k-subtiles of 32 ----
#pragma unroll
        for (int ks = 0; ks < 2; ++ks) {
            s8v bfrag[NT];
#pragma unroll
            for (int ni = 0; ni < NT; ++ni) {
                const int col = wc * (NT * 16) + ni * 16 + (lane & 15);
                bfrag[ni] = *(const s8v*)&Bbuf[col * 64 + ks * 32 + (lane >> 4) * 8];
            }
#pragma unroll
            for (int mi = 0; mi < 4; ++mi) {
                const int row = wr * 64 + mi * 16 + (lane & 15);
                const s8v af = *(const s8v*)&Abuf[row * 64 + ks * 32 + (lane >> 4) * 8];
#pragma unroll
                for (int ni = 0; ni < NT; ++ni)
                    acc[mi][ni] = __builtin_amdgcn_mfma_f32_16x16x32_bf16(af, bfrag[ni], acc[mi][ni], 0, 0, 0);
            }
        }
        __syncthreads();
    }

    // ---- epilogue: C/D layout col=lane&15, row=(lane>>4)*4+reg ----
#pragma unroll
    for (int mi = 0; mi < 4; ++mi) {
#pragma unroll
        for (int reg = 0; reg < 4; ++reg) {
            const int row = rbase + wr * 64 + mi * 16 + (lane >> 4) * 4 + reg;
            if (row >= M) continue;
            const float rs = SCALE ? rowscale[row] : 1.f;
#pragma unroll
            for (int ni = 0; ni < NT; ++ni) {
                const int col = bn + wc * (NT * 16) + ni * 16 + (lane & 15);
                float v = acc[mi][ni][reg];
                if (SCALE) v *= rs;
                if (bias) v += bias[col];
                if (RELU) v = fmaxf(v, 0.f);
                if constexpr (OUTMODE == 2) {
                    Ch[(size_t)row * Nout + col] = f2bf(v);
                } else if constexpr (OUTMODE == 3) {
                    Cf[(size_t)row * Nout + col] = v;
                    Ch[(size_t)row * Nout + col] = f2bf(v);
                } else {
                    Cf[(size_t)row * Nout + col] = v;
                }
            }
        }
    }
}

// ---------------- weight transpose + bf16 convert ---------------------------
struct WDesc { const float* W; ushort_t* h; int K; int No; };
struct WAll { WDesc d[6]; };

__global__ void wtcvt_kernel(WAll wa) {
    WDesc d = wa.d[blockIdx.y];
    int e = blockIdx.x * blockDim.x + threadIdx.x;
    if (e >= d.K * d.No) return;
    int k = e / d.No, n = e - k * d.No;
    d.h[(size_t)n * d.K + k] = f2bf(d.W[e]);
}

// ---------------- bucketed CSR build ----------------------------------------
__global__ __launch_bounds__(256) void bcount_kernel(const int* __restrict__ dst,
                                                     int* __restrict__ bcount, int E, int NB) {
    __shared__ int cnt[256];
    const int t = threadIdx.x;
    if (t < NB) cnt[t] = 0;
    __syncthreads();
    for (int e = blockIdx.x * 256 + t; e < E; e += gridDim.x * 256)
        atomicAdd(&cnt[dst[e] >> BSHIFT], 1);
    __syncthreads();
    if (t < NB && cnt[t]) atomicAdd(&bcount[t], cnt[t]);
}

__global__ __launch_bounds__(256) void bscan_kernel(const int* __restrict__ bcount,
                                                    int* __restrict__ bbase,
                                                    int* __restrict__ bcursor, int NB, int E) {
    __shared__ int s[256];
    const int t = threadIdx.x;
    s[t] = (t < NB) ? bcount[t] : 0;
    __syncthreads();
    for (int off = 1; off < 256; off <<= 1) {
        int v = (t >= off) ? s[t - off] : 0;
        __syncthreads();
        s[t] += v;
        __syncthreads();
    }
    int excl = t ? s[t - 1] : 0;
    if (t < NB) { bbase[t] = excl; bcursor[t] = excl; }
    if (t == 0) bbase[NB] = E;
}

__global__ __launch_bounds__(256) void bpart_kernel(const int* __restrict__ src,
                                                    const int* __restrict__ dst,
                                                    int* __restrict__ bcursor,
                                                    unsigned* __restrict__ packed, int E, int NB) {
    __shared__ int cnt[256];
    __shared__ int cur[256];
    const int t = threadIdx.x;
    const int beg = blockIdx.x * 8192;
    const int end = min(beg + 8192, E);
    if (t < NB) cnt[t] = 0;
    __syncthreads();
    for (int e = beg + t; e < end; e += 256) atomicAdd(&cnt[dst[e] >> BSHIFT], 1);
    __syncthreads();
    if (t < NB && cnt[t]) cur[t] = atomicAdd(&bcursor[t], cnt[t]);
    __syncthreads();
    for (int e = beg + t; e < end; e += 256) {
        int d = dst[e];
        int b = d >> BSHIFT;
        int pos = atomicAdd(&cur[b], 1);
        packed[pos] = (unsigned)src[e] | ((unsigned)(d & ((1 << BSHIFT) - 1)) << 16);
    }
}

__global__ __launch_bounds__(256) void bbuild_kernel(const int* __restrict__ bbase,
                                                     const unsigned* __restrict__ packed,
                                                     int* __restrict__ col,
                                                     int* __restrict__ rowstart,
                                                     float* __restrict__ dinv, int N, int E) {
    __shared__ int ncnt[256];
    __shared__ int s[256];
    __shared__ int ncur[256];
    const int b = blockIdx.x;
    const int t = threadIdx.x;
    const int beg = bbase[b], end = bbase[b + 1];
    const int node0 = b << BSHIFT;
    const int nInB = min(256, N - node0);
    ncnt[t] = 0;
    __syncthreads();
    for (int e = beg + t; e < end; e += 256) atomicAdd(&ncnt[packed[e] >> 16], 1);
    __syncthreads();
    s[t] = ncnt[t];
    __syncthreads();
    for (int off = 1; off < 256; off <<= 1) {
        int v = (t >= off) ? s[t - off] : 0;
        __syncthreads();
        s[t] += v;
        __syncthreads();
    }
    int excl = t ? s[t - 1] : 0;
    if (t < nInB) {
        rowstart[node0 + t] = beg + excl;
        dinv[node0 + t] = rsqrtf((float)ncnt[t] + 1.0f);
    }
    ncur[t] = beg + excl;
    __syncthreads();
    for (int e = beg + t; e < end; e += 256) {
        unsigned p = packed[e];
        int pos = atomicAdd(&ncur[p >> 16], 1);
        col[pos] = (int)(p & 0xFFFFu);
    }
    if (b == 0 && t == 0) rowstart[N] = E;
}

// ---------------- CSR gather (bf16 in, bf16 out, 8-deep ILP) ----------------
template <int F>
__global__ __launch_bounds__(256) void gather_bf_kernel(const int* __restrict__ rowstart,
                                                        const int* __restrict__ col,
                                                        const float* __restrict__ dinv,
                                                        const ushort_t* __restrict__ hws,
                                                        const float* __restrict__ bias,
                                                        ushort_t* __restrict__ aggb, int N) {
    const int wave = threadIdx.x >> 6;
    const int lane = threadIdx.x & 63;
    const int d = blockIdx.x * 4 + wave;
    if (d >= N) return;
    const int beg = rowstart[d], end = rowstart[d + 1];
    const float dd = dinv[d];
    if (F == 128) {
        const unsigned* base = (const unsigned*)hws;   // 2 bf16 per uint
        unsigned sv = base[(size_t)d * 64 + lane];
        float ax = __uint_as_float(sv << 16);
        float ay = __uint_as_float(sv & 0xFFFF0000u);
        for (int e0 = beg; e0 < end; e0 += 64) {
            int nid = (e0 + lane < end) ? col[e0 + lane] : 0;
            int cnt = min(64, end - e0);
            int j = 0;
            for (; j + 8 <= cnt; j += 8) {
                unsigned u[8];
#pragma unroll
                for (int q = 0; q < 8; ++q) {
                    int s = __shfl(nid, j + q);
                    u[q] = base[(size_t)s * 64 + lane];
                }
#pragma unroll
                for (int q = 0; q < 8; ++q) {
                    ax += __uint_as_float(u[q] << 16);
                    ay += __uint_as_float(u[q] & 0xFFFF0000u);
                }
            }
            for (; j < cnt; ++j) {
                int s = __shfl(nid, j);
                unsigned uu = base[(size_t)s * 64 + lane];
                ax += __uint_as_float(uu << 16);
                ay += __uint_as_float(uu & 0xFFFF0000u);
            }
        }
        float2 b = ((const float2*)bias)[lane];
        float rx = fmaxf(ax * dd + b.x, 0.f);
        float ry = fmaxf(ay * dd + b.y, 0.f);
        unsigned pk = ((unsigned)f2bf(ry) << 16) | (unsigned)f2bf(rx);
        ((unsigned*)aggb)[(size_t)d * 64 + lane] = pk;
    } else {  // F == 64
        float acc = __uint_as_float((unsigned)hws[(size_t)d * 64 + lane] << 16);
        for (int e0 = beg; e0 < end; e0 += 64) {
            int nid = (e0 + lane < end) ? col[e0 + lane] : 0;
            int cnt = min(64, end - e0);
            int j = 0;
            for (; j + 8 <= cnt; j += 8) {
                ushort_t u[8];
#pragma unroll
                for (int q = 0; q < 8; ++q) {
                    int s = __shfl(nid, j + q);
                    u[q] = hws[(size_t)s * 64 + lane];
                }
#pragma unroll
                for (int q = 0; q < 8; ++q) acc += __uint_as_float((unsigned)u[q] << 16);
            }
            for (; j < cnt; ++j) {
                int s = __shfl(nid, j);
                acc += __uint_as_float((unsigned)hws[(size_t)s * 64 + lane] << 16);
            }
        }
        acc = fmaxf(acc * dd + bias[lane], 0.f);
        aggb[(size_t)d * 64 + lane] = f2bf(acc);
    }
}

// ---------------- edge decode (bf16 emb1 copy) ------------------------------
__global__ __launch_bounds__(256) void decode_kernel(const ushort_t* __restrict__ emb1b,
                                                     const int* __restrict__ eli,
                                                     const float* __restrict__ Wpost,
                                                     const float* __restrict__ bpost,
                                                     float* __restrict__ pred, int L) {
    const int wave = threadIdx.x >> 6;
    const int lane = threadIdx.x & 63;
    const int l = blockIdx.x * 4 + wave;
    if (l >= L) return;
    int s = eli[l];
    int d = eli[L + l];
    float w = Wpost[lane * 2] + Wpost[lane * 2 + 1];
    float a = __uint_as_float((unsigned)emb1b[(size_t)s * 64 + lane] << 16);
    float b = __uint_as_float((unsigned)emb1b[(size_t)d * 64 + lane] << 16);
    float p = a * b * w;
#pragma unroll
    for (int off = 32; off; off >>= 1) p += __shfl_down(p, off);
    if (lane == 0) pred[l] = p + bpost[0] + bpost[1];
}

// ---------------------------------------------------------------------------
extern "C" void kernel_launch(void* const* d_in, const int* in_sizes, int n_in,
                              void* d_out, int out_size, void* d_ws, size_t ws_size,
                              hipStream_t stream) {
    const float* x     = (const float*)d_in[0];
    const float* prev0 = (const float*)d_in[1];
    const float* prev1 = (const float*)d_in[2];
    const float* Wpre1 = (const float*)d_in[3];
    const float* bpre1 = (const float*)d_in[4];
    const float* Wpre2 = (const float*)d_in[5];
    const float* bpre2 = (const float*)d_in[6];
    const float* Wc1   = (const float*)d_in[7];
    const float* bc1   = (const float*)d_in[8];
    const float* Wc2   = (const float*)d_in[9];
    const float* bc2   = (const float*)d_in[10];
    const float* Wm1   = (const float*)d_in[11];
    const float* bm1   = (const float*)d_in[12];
    const float* Wm2   = (const float*)d_in[13];
    const float* bm2   = (const float*)d_in[14];
    const float* Wpost = (const float*)d_in[15];
    const float* bpost = (const float*)d_in[16];
    const int* edge_index = (const int*)d_in[17];
    const int* eli        = (const int*)d_in[18];

    const int N = in_sizes[0] / 256;   // 50000  (must be <= 65536 for packing)
    const int E = in_sizes[17] / 2;    // 1.6M
    const int L = in_sizes[18] / 2;    // 200K
    const int NB = (N + 255) >> BSHIFT;

    const int* src = edge_index;
    const int* dst = edge_index + E;

    float* out  = (float*)d_out;
    float* pred = out;                        // [L]
    float* emb0 = out + L;                    // [N,128]
    float* emb1 = out + L + (size_t)N * 128;  // [N,64]

    // ---- workspace layout (FLOAT-SLOT offsets; R14 map, verified passing) ----
    //  packed  [0,32N)     bpart->bbuild (pre-G1)
    //  h1h     [0,128N)    G1->G2          hws1b [0,64N)   G3->gather1
    //  emb0b   [0,64N)     G5->G6          emb1b [0,32N)   G8->decode
    //  agg1b   [64N,128N)  gather1->G5     hws2b [64N,96N) G6->gather2
    //  agg2b   [96N,128N)  gather2->G8
    //  h2b     [128N,192N) G2->G3
    //  p0b     [192N,256N) cvt->G5         p1b   [256N,288N) cvt->G8
    //  col     [288N,320N) build->end      tail @320N: rowstart,dinv,buckets,wb
    float* ws = (float*)d_ws;
    unsigned* packed = (unsigned*)ws;
    ushort_t* h1h   = (ushort_t*)ws;
    ushort_t* hws1b = (ushort_t*)ws;
    ushort_t* emb0b = (ushort_t*)ws;
    ushort_t* emb1b = (ushort_t*)ws;
    ushort_t* agg1b = (ushort_t*)(ws + (size_t)64 * N);
    ushort_t* hws2b = (ushort_t*)(ws + (size_t)64 * N);
    ushort_t* agg2b = (ushort_t*)(ws + (size_t)96 * N);
    ushort_t* h2b   = (ushort_t*)(ws + (size_t)128 * N);
    ushort_t* p0b   = (ushort_t*)(ws + (size_t)192 * N);
    ushort_t* p1b   = (ushort_t*)(ws + (size_t)256 * N);
    int*      col   = (int*)(ws + (size_t)288 * N);

    size_t o = (size_t)320 * N;
    int* rowstart = (int*)(ws + o);         o += ((size_t)N + 4) & ~(size_t)3;
    float* dinv = ws + o;                   o += ((size_t)N + 3) & ~(size_t)3;
    int* bbase = (int*)(ws + o);            o += 260;
    int* bcursor = (int*)(ws + o);          o += 260;
    int* bcount = (int*)(ws + o);           o += 260;
    ushort_t* wb = (ushort_t*)(ws + o);     // 163840 ushorts (16B-aligned)

    // transposed bf16 weight offsets (ushorts) within wb
    ushort_t* wpre1t = wb + 0;        // [256][256]
    ushort_t* wpre2t = wb + 65536;    // [128][256]
    ushort_t* wc1t   = wb + 98304;    // [128][128]
    ushort_t* wm1t   = wb + 114688;   // [128][256]
    ushort_t* wc2t   = wb + 147456;   // [64][128]
    ushort_t* wm2t   = wb + 155648;   // [64][128]

    // 0) prev0/prev1 -> bf16
    {
        size_t n0 = (size_t)N * 128, n1 = (size_t)N * 64;
        f2b_kernel<<<(int)((n0 / 8 + 255) / 256), 256, 0, stream>>>(prev0, p0b, n0);
        f2b_kernel<<<(int)((n1 / 8 + 255) / 256), 256, 0, stream>>>(prev1, p1b, n1);
    }

    // 0a) bucketed CSR build + dinv (packed aliases h1h region; done pre-G1)
    hipMemsetAsync(bcount, 0, (size_t)NB * sizeof(int), stream);
    bcount_kernel<<<1024, 256, 0, stream>>>(dst, bcount, E, NB);
    bscan_kernel<<<1, 256, 0, stream>>>(bcount, bbase, bcursor, NB, E);
    bpart_kernel<<<(E + 8191) / 8192, 256, 0, stream>>>(src, dst, bcursor, packed, E, NB);
    bbuild_kernel<<<NB, 256, 0, stream>>>(bbase, packed, col, rowstart, dinv, N, E);

    // 0b) weights: transpose + bf16 convert ([Nout][K] row-major)
    WAll wa;
    wa.d[0] = {Wpre1, wpre1t, 256, 256};
    wa.d[1] = {Wpre2, wpre2t, 256, 128};
    wa.d[2] = {Wc1,   wc1t,   128, 128};
    wa.d[3] = {Wm1,   wm1t,   256, 128};
    wa.d[4] = {Wc2,   wc2t,   128, 64};
    wa.d[5] = {Wm2,   wm2t,   128, 64};
    wtcvt_kernel<<<dim3(256, 6), 256, 0, stream>>>(wa);

    const int gy = (N + 127) / 128;   // 391 row blocks

    // 1) h1 = bf16(relu(x@Wpre1+b))           [N,256]  K=256, fp32 A reg-staged
    gemm_lds<128, 256, 256, true, true, false, false, 2><<<dim3(2, gy), 256, 0, stream>>>(
        x, nullptr, nullptr, wpre1t, bpre1, nullptr, nullptr, h1h, N, 256);
    // 2) h2 = bf16(relu(h1@Wpre2+b))          [N,128]  K=256, DMA
    gemm_lds<128, 256, 256, false, true, false, false, 2><<<dim3(1, gy), 256, 0, stream>>>(
        nullptr, h1h, nullptr, wpre2t, bpre2, nullptr, nullptr, h2b, N, 128);
    // 3) hws1 = bf16((h2@Wc1)*dinv[row])      [N,128]  K=128  (h1 dead)
    gemm_lds<128, 128, 128, false, false, true, false, 2><<<dim3(1, gy), 256, 0, stream>>>(
        nullptr, h2b, nullptr, wc1t, nullptr, dinv, nullptr, hws1b, N, 128);
    // 4) agg1 = bf16(relu(dinv*(hws1[d]+sum hws1[s])+bc1))
    gather_bf_kernel<128><<<(N + 3) / 4, 256, 0, stream>>>(rowstart, col, dinv, hws1b, bc1, agg1b, N);
    // 5) emb0 = [agg1,prev0]@Wm1+bm1 (fp32 + bf16 copy)  [N,128]  K=128+128
    gemm_lds<128, 256, 128, false, false, false, true, 3><<<dim3(1, gy), 256, 0, stream>>>(
        nullptr, agg1b, p0b, wm1t, bm1, nullptr, emb0, emb0b, N, 128);
    // 6) hws2 = bf16((emb0@Wc2)*dinv[row])    [N,64]   K=128
    gemm_lds<64, 128, 128, false, false, true, false, 2><<<dim3(1, gy), 256, 0, stream>>>(
        nullptr, emb0b, nullptr, wc2t, nullptr, dinv, nullptr, hws2b, N, 64);
    // 7) agg2 = bf16(relu(dinv*(hws2[d]+sum hws2[s])+bc2))
    gather_bf_kernel<64><<<(N + 3) / 4, 256, 0, stream>>>(rowstart, col, dinv, hws2b, bc2, agg2b, N);
    // 8) emb1 = [agg2,prev1]@Wm2+bm2 (fp32 + bf16 copy)  [N,64]  K=64+64
    gemm_lds<64, 128, 64, false, false, false, true, 3><<<dim3(1, gy), 256, 0, stream>>>(
        nullptr, agg2b, p1b, wm2t, bm2, nullptr, emb1, emb1b, N, 64);
    // 9) decode (bf16 emb1 copy, L2-resident)
    decode_kernel<<<(L + 3) / 4, 256, 0, stream>>>(emb1b, eli, Wpost, bpost, pred, L);
}